// Round 6
// baseline (619.848 us; speedup 1.0000x reference)
//
#include <hip/hip_runtime.h>
#include <hip/hip_bf16.h>
#include <math.h>

#define BATCH 2
#define RES   32
#define LTOK  32768          // RES^3
#define CDIM  288
#define NQKV  864
#define MROWS 65536          // BATCH*LTOK

typedef unsigned short u16;
typedef u16   u16x4 __attribute__((ext_vector_type(4)));
typedef short s16x8 __attribute__((ext_vector_type(8)));   // 8 bf16 in 4 VGPRs (MFMA A/B frag)
typedef float f32x4 __attribute__((ext_vector_type(4)));   // MFMA C/D frag

__device__ __forceinline__ u16 f2bf(float f) {
  union { __hip_bfloat16 h; u16 u; } x;
  x.h = __float2bfloat16(f);
  return x.u;
}
__device__ __forceinline__ float bf2f(u16 u) {
  union { u16 u; __hip_bfloat16 h; } x;
  x.u = u;
  return __bfloat162float(x.h);
}
// bf16 pair unpack from packed u32 (lo = even channel, hi = odd channel)
__device__ __forceinline__ float bflo(unsigned u) {
  union { unsigned u; float f; } x; x.u = u << 16; return x.f;
}
__device__ __forceinline__ float bfhi(unsigned u) {
  union { unsigned u; float f; } x; x.u = u & 0xffff0000u; return x.f;
}

// async 16B global->LDS copy (per-lane global src, wave-uniform LDS base + lane*16)
#define ASYNC16(gsrc, ldst)                                                        \
  __builtin_amdgcn_global_load_lds(                                                \
      (const __attribute__((address_space(1))) void*)(gsrc),                       \
      (__attribute__((address_space(3))) void*)(ldst), 16, 0, 0)

// ---------------- weight transpose+convert: W (K x N) f32 -> Wt (N x K) bf16 ----------------
__global__ __launch_bounds__(256) void transpose_cvt(
    const float* __restrict__ w, u16* __restrict__ wt, int K, int N) {
  int o = blockIdx.x * 256 + threadIdx.x;
  if (o >= N * K) return;
  int n = o / K, k = o - n * K;
  wt[o] = f2bf(w[(size_t)k * N + n]);
}

// conv weights (C,1,3,3,3) -> k-major [27][288]
__global__ __launch_bounds__(256) void conv_w_kmajor(
    const float* __restrict__ cw, float* __restrict__ wck) {
  int o = blockIdx.x * 256 + threadIdx.x;
  if (o >= 27 * 288) return;
  int k = o / 288, c = o - k * 288;
  wck[o] = cw[c * 27 + k];
}

// ---------------- A-resident GEMM, B-from-L2: out = A(M x 288) @ Bt(N x 288)^T ----------------
// Block = 64 A-rows staged ONCE into LDS [36][64][16B] (granule-major; 2-way bank alias = free).
// 4 waves; wave w independently computes whole 64x32 output chunks c = w, w+4, ...
// (4 m-frags x 2 n-frags, 8 acc streams). A-frags from LDS (each read feeds 2 MFMAs);
// B-frags straight from global (Bt is <=497KB -> L2-resident; per (ks,ni) the wave
// reads 16 rows x 64B lines -> fully coalesced). NO barriers after the A stage.
template <bool BF16OUT, bool ABF16>
__global__ __launch_bounds__(256, 4) void gemm_ares(
    const void* __restrict__ Ax, const u16* __restrict__ Bt,
    const float* __restrict__ bias, void* __restrict__ out, int N) {
  __shared__ __align__(16) u16 As[18432];   // [36 granules][64 rows][8 u16]
  const int bm = blockIdx.x * 64;
  const int tid = threadIdx.x;
  const int lane = tid & 63, wave = tid >> 6;
  const int m16 = lane & 15, kq = lane >> 4;
  const int NC = N >> 5;                    // 32-col chunks

  // ---- A prologue: 64 x 288 bf16 -> LDS ----
  if (ABF16) {
    const u16* Ab = (const u16*)Ax;
    for (int g = wave; g < 36; g += 4)
      ASYNC16(Ab + (size_t)(bm + lane) * 288 + g * 8, &As[g * 512]);
    asm volatile("s_waitcnt vmcnt(0)" ::: "memory");
  } else {
    const float* Af = (const float*)Ax;
#pragma unroll
    for (int p = 0; p < 18; p++) {          // 4608 float4 / 256 thr
      int s = p * 256 + tid;
      int g2 = s >> 7, r2 = (s & 127) >> 1, half = s & 1;
      float4 v = *(const float4*)(Af + (size_t)(bm + r2) * 288 + g2 * 8 + half * 4);
      u16x4 pk;
      pk[0] = f2bf(v.x); pk[1] = f2bf(v.y); pk[2] = f2bf(v.z); pk[3] = f2bf(v.w);
      *(u16x4*)&As[g2 * 512 + r2 * 8 + half * 4] = pk;
    }
  }
  __syncthreads();

  for (int c = wave; c < NC; c += 4) {
    const u16* Bc = Bt + ((size_t)c << 5) * 288;
    f32x4 acc[4][2];
#pragma unroll
    for (int mi = 0; mi < 4; mi++)
#pragma unroll
      for (int ni = 0; ni < 2; ni++) acc[mi][ni] = (f32x4){0.f, 0.f, 0.f, 0.f};

#pragma unroll
    for (int ks = 0; ks < 9; ks++) {
      s16x8 bf[2];
#pragma unroll
      for (int ni = 0; ni < 2; ni++)
        bf[ni] = *(const s16x8*)(Bc + (size_t)(ni * 16 + m16) * 288 + ks * 32 + kq * 8);
      const int g = ks * 4 + kq;
#pragma unroll
      for (int mi = 0; mi < 4; mi++) {
        s16x8 af = *(const s16x8*)&As[g * 512 + (mi * 16 + m16) * 8];
#pragma unroll
        for (int ni = 0; ni < 2; ni++)
          acc[mi][ni] = __builtin_amdgcn_mfma_f32_16x16x32_bf16(af, bf[ni], acc[mi][ni], 0, 0, 0);
      }
    }
    // epilogue: D layout col=lane&15, row=(lane>>4)*4+r
    if (BF16OUT) {
      u16* op = (u16*)out;
#pragma unroll
      for (int mi = 0; mi < 4; mi++)
#pragma unroll
        for (int ni = 0; ni < 2; ni++)
#pragma unroll
          for (int r = 0; r < 4; r++)
            op[(size_t)(bm + mi * 16 + kq * 4 + r) * N + (c << 5) + ni * 16 + m16] =
                f2bf(acc[mi][ni][r]);
    } else {
      float* op = (float*)out;
#pragma unroll
      for (int ni = 0; ni < 2; ni++) {
        const int col = (c << 5) + ni * 16 + m16;
        const float bv = bias ? bias[col] : 0.f;
#pragma unroll
        for (int mi = 0; mi < 4; mi++)
#pragma unroll
          for (int r = 0; r < 4; r++)
            op[(size_t)(bm + mi * 16 + kq * 4 + r) * N + col] = acc[mi][ni][r] + bv;
      }
    }
  }
}

// ---------------- tiny RPE-bias MLP: (3,63,3) -> (3,63,4) ----------------
__device__ __forceinline__ void ln_relu6(const float* x, float* o,
                                         const float* g, const float* b) {
  float m = 0.f;
#pragma unroll
  for (int i = 0; i < 6; i++) m += x[i];
  m *= (1.f / 6.f);
  float v = 0.f;
#pragma unroll
  for (int i = 0; i < 6; i++) { float d = x[i] - m; v += d * d; }
  v *= (1.f / 6.f);
  float r = rsqrtf(v + 1e-5f);
#pragma unroll
  for (int i = 0; i < 6; i++) {
    float t = (x[i] - m) * r * g[i] + b[i];
    o[i] = t > 0.f ? t : 0.f;
  }
}

__global__ __launch_bounds__(256) void rpe_mlp(
    const float* __restrict__ rpe, const float* __restrict__ pw, const float* __restrict__ pb,
    const float* __restrict__ g1, const float* __restrict__ b1,
    const float* __restrict__ w1, const float* __restrict__ bb1,
    const float* __restrict__ g2, const float* __restrict__ b2,
    const float* __restrict__ w2, const float* __restrict__ bb2,
    const float* __restrict__ g3, const float* __restrict__ b3,
    const float* __restrict__ w3, const float* __restrict__ bb3,
    float* __restrict__ ptab) {
  int t = blockIdx.x * blockDim.x + threadIdx.x;
  if (t >= 3 * 63) return;
  int bi = t / 63, row = t % 63;
  float p[6], q[6];
#pragma unroll
  for (int j = 0; j < 6; j++) {
    float s = pb[bi * 6 + j];
#pragma unroll
    for (int i = 0; i < 3; i++) s += rpe[(bi * 63 + row) * 3 + i] * pw[(bi * 3 + i) * 6 + j];
    p[j] = s;
  }
  ln_relu6(p, q, g1 + bi * 6, b1 + bi * 6);
#pragma unroll
  for (int j = 0; j < 6; j++) {
    float s = bb1[bi * 6 + j];
#pragma unroll
    for (int i = 0; i < 6; i++) s += q[i] * w1[(bi * 6 + i) * 6 + j];
    p[j] = s;
  }
  ln_relu6(p, q, g2 + bi * 6, b2 + bi * 6);
#pragma unroll
  for (int j = 0; j < 6; j++) {
    float s = bb2[bi * 6 + j];
#pragma unroll
    for (int i = 0; i < 6; i++) s += q[i] * w2[(bi * 6 + i) * 6 + j];
    p[j] = s;
  }
  ln_relu6(p, q, g3 + bi * 6, b3 + bi * 6);
#pragma unroll
  for (int h = 0; h < 4; h++) {
    float s = bb3[bi * 4 + h];
#pragma unroll
    for (int i = 0; i < 6; i++) s += q[i] * w3[(bi * 6 + i) * 4 + h];
    ptab[(bi * 63 + row) * 4 + h] = s;
  }
}

// ---------------- windowed attention via MFMA: 4 windows per 256-thr block ----------------
// One wave per window, fully independent (private LDS slices, ZERO barriers --
// all LDS dependencies are intra-wave; compiler inserts the lgkmcnt waits).
// Per (window, head): score = mfma(Qfrag,Kfrag) [K=32, ch24..31 zero]; quad-wide
// softmax via shfl_xor; P stored hi+lo bf16 in k=0..15/16..31 against duplicated
// V^T cols -> ~f32-precision PV at no extra MFMA cost. 25.6 KB LDS/block ->
// 6 blocks/CU = 24 waves/CU (64-thr blocks capped at 16 via the workgroup limit).
__global__ __launch_bounds__(256) void attn_kernel(
    const u16* __restrict__ qkv, const float* __restrict__ ptab,
    const int* __restrict__ rel, float* __restrict__ y) {
  __shared__ __align__(16) u16 sq[4][640];     // [n][40]: k 0..23 data, 24..31 zero
  __shared__ __align__(16) u16 sk[4][640];
  __shared__ __align__(16) u16 svt[4][1280];   // [ch][40]: cols 0..15 V^T, 16..31 dup; rows 24..31 zero
  __shared__ __align__(16) u16 sps[4][640];    // [n][40]: m 0..15 hi, 16..31 lo

  const int bi = blockIdx.y;
  const int wsh = (bi == 2) ? 1 : 2;            // log2(Wsp)
  const int hsh = (bi == 2) ? 2 : 1;            // log2(Hsp)
  const int Wm1 = (1 << wsh) - 1, Hm1 = (1 << hsh) - 1;
  const int nW = RES >> wsh, nH = RES >> hsh;
  const int tid = threadIdx.x;
  const int wv = tid >> 6, lane = tid & 63;
  const int wid = blockIdx.x * 4 + wv;          // 0..4095
  const int b = wid >> 11;
  const int r_ = wid & 2047;
  const int w0 = r_ % nW;
  const int r2 = r_ / nW;
  const int h0 = r2 % nH;
  const int d0 = r2 / nH;

  u16* q_  = sq[wv];
  u16* k_  = sk[wv];
  u16* vt_ = svt[wv];
  u16* ps_ = sps[wv];
  const int m16 = lane & 15, q4 = lane >> 4;

  // ---- zero ONLY the pad regions (never rewritten by staging) ----
  {
    uint4 z = make_uint4(0u, 0u, 0u, 0u);
    if (lane < 16) {
      *(uint4*)&q_[lane * 40 + 24] = z;
      *(uint4*)&k_[lane * 40 + 24] = z;
    }
    if (lane < 40) {                      // svt rows 24..31, full 40-u16 rows
      int row = 24 + lane / 5, ch = (lane % 5) * 8;
      *(uint4*)&vt_[row * 40 + ch] = z;
    }
  }

  // rel gather (head-invariant): rv[r] for n = q4*4+r, m = m16
  int rv[4];
#pragma unroll
  for (int r = 0; r < 4; r++) rv[r] = rel[(bi * 16 + q4 * 4 + r) * 16 + m16];

  // per-row global y bases for n = q4*4+r
  size_t ybase[4];
#pragma unroll
  for (int r = 0; r < 4; r++) {
    int n = q4 * 4 + r;
    int dd = n >> 3, hh2 = (n >> wsh) & Hm1, ww = n & Wm1;
    int l = ((d0 * 2 + dd) * RES + ((h0 << hsh) + hh2)) * RES + ((w0 << wsh) + ww);
    ybase[r] = (size_t)(b * LTOK + l) * CDIM + bi * 96;
  }

  const float scale = 0.20412414523193154f;  // 1/sqrt(24)

  for (int hd = 0; hd < 4; hd++) {
    // ---- stage q,k,v: 16 tokens x 24 ch in 16B chunks (3 per token per array) ----
    if (lane < 48) {
      int n = lane / 3, ch = (lane % 3) * 8;
      int dd = n >> 3, hh2 = (n >> wsh) & Hm1, ww = n & Wm1;
      int l = ((d0 * 2 + dd) * RES + ((h0 << hsh) + hh2)) * RES + ((w0 << wsh) + ww);
      size_t base = (size_t)(b * LTOK + l) * NQKV + bi * 96 + hd * 24 + ch;
      uint4 qv = *(const uint4*)(qkv + base);
      uint4 kv = *(const uint4*)(qkv + base + 288);
      uint4 vv = *(const uint4*)(qkv + base + 576);
      *(uint4*)&q_[n * 40 + ch] = qv;
      *(uint4*)&k_[n * 40 + ch] = kv;
      const u16* vp = (const u16*)&vv;
#pragma unroll
      for (int j = 0; j < 8; j++) {
        vt_[(ch + j) * 40 + n] = vp[j];
        vt_[(ch + j) * 40 + 16 + n] = vp[j];
      }
    }

    // ---- scores: one MFMA (D: col=m16 -> key m, rows q4*4+r -> query n) ----
    s16x8 af = *(const s16x8*)&q_[m16 * 40 + q4 * 8];
    s16x8 bf = *(const s16x8*)&k_[m16 * 40 + q4 * 8];
    f32x4 sc = __builtin_amdgcn_mfma_f32_16x16x32_bf16(af, bf, (f32x4){0.f, 0.f, 0.f, 0.f}, 0, 0, 0);

    float inv[4];
#pragma unroll
    for (int r = 0; r < 4; r++) {
      float s = sc[r] * scale + ptab[(size_t)(bi * 63 + rv[r]) * 4 + hd];
      float mx = s;
#pragma unroll
      for (int msk = 1; msk <= 8; msk <<= 1) mx = fmaxf(mx, __shfl_xor(mx, msk));
      float e = expf(s - mx);
      float sum = e;
#pragma unroll
      for (int msk = 1; msk <= 8; msk <<= 1) sum += __shfl_xor(sum, msk);
      inv[r] = 1.f / sum;
      u16 hi = f2bf(e);
      float lo = e - bf2f(hi);
      ps_[(q4 * 4 + r) * 40 + m16] = hi;
      ps_[(q4 * 4 + r) * 40 + 16 + m16] = f2bf(lo);
    }

    // ---- PV: 2 MFMAs (A = P hi|lo over k=0..31; B = svt rows ch, ch+16) ----
    s16x8 pa = *(const s16x8*)&ps_[m16 * 40 + q4 * 8];
    s16x8 v1 = *(const s16x8*)&vt_[m16 * 40 + q4 * 8];
    s16x8 v2 = *(const s16x8*)&vt_[(16 + m16) * 40 + q4 * 8];
    f32x4 o1 = __builtin_amdgcn_mfma_f32_16x16x32_bf16(pa, v1, (f32x4){0.f, 0.f, 0.f, 0.f}, 0, 0, 0);
    f32x4 o2 = __builtin_amdgcn_mfma_f32_16x16x32_bf16(pa, v2, (f32x4){0.f, 0.f, 0.f, 0.f}, 0, 0, 0);

#pragma unroll
    for (int r = 0; r < 4; r++) {
      float* yp = y + ybase[r] + hd * 24;
      yp[m16] = o1[r] * inv[r];
      if (m16 < 8) yp[16 + m16] = o2[r] * inv[r];
    }
  }
}

// ---------------- depthwise 3x3x3 conv on V (bf16) ----------------
// one block = 8x8x8 token tile x 32 channels, 512 threads (1 token/thread).
// Halo 10^3 tokens staged bf16, token stride 40 u16 (80 B, conflict-free spread).
// Weights k-major [27][288]: 32 contiguous floats per tap (uniform s_loads).
template <bool BF16OUT>
__global__ __launch_bounds__(512, 4) void conv_tile_kernel(
    const u16* __restrict__ qkv, const float* __restrict__ wck,
    const float* __restrict__ cb, float* __restrict__ y, u16* __restrict__ ybf) {
  __shared__ __align__(16) u16 vs[1000 * 40];   // 80000 B
  const int tid = threadIdx.x;
  const int bx = blockIdx.x;           // 0..127 : b*64 + tile
  const int c0 = blockIdx.y * 32;      // channel group 0..8
  const int b = bx >> 6;
  const int t = bx & 63;
  const int td = (t >> 4) * 8, th = ((t >> 2) & 3) * 8, tw = (t & 3) * 8;

  // ---- stage V halo tile (10x10x10 tokens x 32 ch bf16) ----
#pragma unroll
  for (int p = 0; p < 8; p++) {
    int idx = p * 512 + tid;           // 4 chunks of 16B per token
    if (idx < 4000) {
      int tok = idx >> 2, chunk = idx & 3;
      int dz = tok / 100, rem = tok - dz * 100;
      int hz = rem / 10, wz = rem - hz * 10;
      int d = td + dz - 1, h = th + hz - 1, w = tw + wz - 1;
      uint4 v = make_uint4(0u, 0u, 0u, 0u);
      if ((unsigned)d < 32u && (unsigned)h < 32u && (unsigned)w < 32u)
        v = *(const uint4*)(qkv +
              ((size_t)(b * LTOK + ((d * 32 + h) * 32 + w))) * NQKV + 576 + c0 + chunk * 8);
      *(uint4*)&vs[tok * 40 + chunk * 8] = v;
    }
  }
  __syncthreads();

  // ---- compute: thread owns token (d,h,w) ----
  const int d = tid >> 6, h = (tid >> 3) & 7, w = tid & 7;
  float acc[32];
#pragma unroll
  for (int c = 0; c < 32; c++) acc[c] = cb[c0 + c];

  for (int kd = 0; kd < 3; kd++) {
#pragma unroll
    for (int kh = 0; kh < 3; kh++) {
#pragma unroll
      for (int kw = 0; kw < 3; kw++) {
        const int k = kd * 9 + kh * 3 + kw;
        const float* wk = wck + k * 288 + c0;   // 32 contiguous uniform floats
        const u16* p0 = &vs[(((d + kd) * 100 + (h + kh) * 10) + (w + kw)) * 40];
#pragma unroll
        for (int cq = 0; cq < 4; cq++) {
          uint4 v0 = *(const uint4*)(p0 + cq * 8);
          const unsigned* u0 = (const unsigned*)&v0;
#pragma unroll
          for (int j = 0; j < 4; j++) {
            const int ce = cq * 8 + j * 2;
            acc[ce]     += bflo(u0[j]) * wk[ce];
            acc[ce + 1] += bfhi(u0[j]) * wk[ce + 1];
          }
        }
      }
    }
  }

  const int tt = b * LTOK + ((td + d) * 32 + (th + h)) * 32 + (tw + w);

  if (BF16OUT) {
    const float4* yp = (const float4*)&y[(size_t)tt * CDIM + c0];
    unsigned pk[16];
#pragma unroll
    for (int q = 0; q < 8; q++) {
      float4 cur = yp[q];
      float va = cur.x + acc[q * 4],     vb = cur.y + acc[q * 4 + 1];
      float vc = cur.z + acc[q * 4 + 2], vd = cur.w + acc[q * 4 + 3];
      pk[q * 2]     = (unsigned)f2bf(va) | ((unsigned)f2bf(vb) << 16);
      pk[q * 2 + 1] = (unsigned)f2bf(vc) | ((unsigned)f2bf(vd) << 16);
    }
    uint4* op = (uint4*)(ybf + (size_t)tt * CDIM + c0);
#pragma unroll
    for (int q = 0; q < 4; q++) op[q] = ((const uint4*)pk)[q];
  } else {
    float4* yp = (float4*)&y[(size_t)tt * CDIM + c0];
#pragma unroll
    for (int q = 0; q < 8; q++) {
      float4 cur = yp[q];
      cur.x += acc[q * 4];     cur.y += acc[q * 4 + 1];
      cur.z += acc[q * 4 + 2]; cur.w += acc[q * 4 + 3];
      yp[q] = cur;
    }
  }
}

extern "C" void kernel_launch(void* const* d_in, const int* in_sizes, int n_in,
                              void* d_out, int out_size, void* d_ws, size_t ws_size,
                              hipStream_t stream) {
  const float* x      = (const float*)d_in[0];
  // d_in[1..3] = D,H,W scalars (fixed 32)
  const float* w_qkv  = (const float*)d_in[4];
  const float* w_proj = (const float*)d_in[5];
  const float* b_proj = (const float*)d_in[6];
  const float* conv_w = (const float*)d_in[7];
  const float* conv_b = (const float*)d_in[8];
  const float* pos_w  = (const float*)d_in[9];
  const float* pos_b  = (const float*)d_in[10];
  const float* ln1_g  = (const float*)d_in[11];
  const float* ln1_b  = (const float*)d_in[12];
  const float* lin1_w = (const float*)d_in[13];
  const float* lin1_b = (const float*)d_in[14];
  const float* ln2_g  = (const float*)d_in[15];
  const float* ln2_b  = (const float*)d_in[16];
  const float* lin2_w = (const float*)d_in[17];
  const float* lin2_b = (const float*)d_in[18];
  const float* ln3_g  = (const float*)d_in[19];
  const float* ln3_b  = (const float*)d_in[20];
  const float* lin3_w = (const float*)d_in[21];
  const float* lin3_b = (const float*)d_in[22];
  const float* rpe    = (const float*)d_in[23];
  const int*   rel    = (const int*)d_in[24];
  float* out = (float*)d_out;

  // ws layout:
  //   [0, Q)         qkv (bf16), Q = 65536*864*2  -- dead after conv
  //   [Q, +497664)   wqt: w_qkv^T bf16 (864 x 288)
  //   [.., +165888)  wpt: w_proj^T bf16 (288 x 288)
  //   [.., +3024)    ptab f32
  //   [.., +31104)   wck f32 (conv weights k-major)
  //   big path: ybf bf16 (37.7 MB) -> conv writes bf16, proj GEMM async-A path
  //   fallback: conv RMW f32 on d_out; proj GEMM in-place d_out->d_out (A-resident => safe)
  const size_t Q = (size_t)MROWS * NQKV * sizeof(u16);
  u16* qkv   = (u16*)d_ws;
  u16* wqt   = (u16*)((char*)d_ws + Q);
  u16* wpt   = (u16*)((char*)d_ws + Q + 497664);
  float* ptab  = (float*)((char*)d_ws + Q + 497664 + 165888);
  float* wck   = (float*)((char*)d_ws + Q + 497664 + 165888 + 3024);

  const size_t yoff = (Q + 497664 + 165888 + 3024 + 31104 + 255) & ~(size_t)255;
  const size_t ybf_bytes = (size_t)MROWS * CDIM * sizeof(u16);
  const bool big = ws_size >= yoff + ybf_bytes;
  u16* ybf = (u16*)((char*)d_ws + yoff);

  // 0. weight transforms (tiny)
  transpose_cvt<<<(NQKV * CDIM + 255) / 256, 256, 0, stream>>>(w_qkv, wqt, CDIM, NQKV);
  transpose_cvt<<<(CDIM * CDIM + 255) / 256, 256, 0, stream>>>(w_proj, wpt, CDIM, CDIM);
  conv_w_kmajor<<<(27 * 288 + 255) / 256, 256, 0, stream>>>(conv_w, wck);
  // 1. qkv = bf16(x @ w_qkv)
  gemm_ares<true, false><<<MROWS / 64, 256, 0, stream>>>(x, wqt, nullptr, qkv, NQKV);
  // 2. rpe bias tables (tiny)
  rpe_mlp<<<1, 256, 0, stream>>>(rpe, pos_w, pos_b, ln1_g, ln1_b, lin1_w, lin1_b,
                                 ln2_g, ln2_b, lin2_w, lin2_b, ln3_g, ln3_b,
                                 lin3_w, lin3_b, ptab);
  // 3. windowed attention (MFMA) -> d_out (f32, fully overwritten)
  attn_kernel<<<dim3(1024, 3), 256, 0, stream>>>(qkv, ptab, rel, out);
  // 4+5. conv add + projection
  if (big) {
    conv_tile_kernel<true><<<dim3(128, 9), 512, 0, stream>>>(qkv, wck, conv_b, out, ybf);
    gemm_ares<false, true><<<MROWS / 64, 256, 0, stream>>>(ybf, wpt, b_proj, out, CDIM);
  } else {
    conv_tile_kernel<false><<<dim3(128, 9), 512, 0, stream>>>(qkv, wck, conv_b, out, nullptr);
    gemm_ares<false, false><<<MROWS / 64, 256, 0, stream>>>(out, wpt, b_proj, out, CDIM);
  }
}

// Round 7
// 391.835 us; speedup vs baseline: 1.5819x; 1.5819x over previous
//
#include <hip/hip_runtime.h>
#include <hip/hip_bf16.h>
#include <math.h>

#define BATCH 2
#define RES   32
#define LTOK  32768          // RES^3
#define CDIM  288
#define NQKV  864
#define MROWS 65536          // BATCH*LTOK

typedef unsigned short u16;
typedef u16   u16x4 __attribute__((ext_vector_type(4)));
typedef short s16x8 __attribute__((ext_vector_type(8)));   // 8 bf16 in 4 VGPRs (MFMA A/B frag)
typedef float f32x4 __attribute__((ext_vector_type(4)));   // MFMA C/D frag

__device__ __forceinline__ u16 f2bf(float f) {
  union { __hip_bfloat16 h; u16 u; } x;
  x.h = __float2bfloat16(f);
  return x.u;
}
__device__ __forceinline__ float bf2f(u16 u) {
  union { u16 u; __hip_bfloat16 h; } x;
  x.u = u;
  return __bfloat162float(x.h);
}
// bf16 pair unpack from packed u32 (lo = even channel, hi = odd channel)
__device__ __forceinline__ float bflo(unsigned u) {
  union { unsigned u; float f; } x; x.u = u << 16; return x.f;
}
__device__ __forceinline__ float bfhi(unsigned u) {
  union { unsigned u; float f; } x; x.u = u & 0xffff0000u; return x.f;
}

// async 16B global->LDS copy (per-lane global src, wave-uniform LDS base + lane*16)
#define ASYNC16(gsrc, ldst)                                                        \
  __builtin_amdgcn_global_load_lds(                                                \
      (const __attribute__((address_space(1))) void*)(gsrc),                       \
      (__attribute__((address_space(3))) void*)(ldst), 16, 0, 0)

// ---------------- weight transpose+convert: W (K x N) f32 -> Wt (N x K) bf16 ----------------
__global__ __launch_bounds__(256) void transpose_cvt(
    const float* __restrict__ w, u16* __restrict__ wt, int K, int N) {
  int o = blockIdx.x * 256 + threadIdx.x;
  if (o >= N * K) return;
  int n = o / K, k = o - n * K;
  wt[o] = f2bf(w[(size_t)k * N + n]);
}

// conv weights (C,1,3,3,3) -> k-major [27][288]
__global__ __launch_bounds__(256) void conv_w_kmajor(
    const float* __restrict__ cw, float* __restrict__ wck) {
  int o = blockIdx.x * 256 + threadIdx.x;
  if (o >= 27 * 288) return;
  int k = o / 288, c = o - k * 288;
  wck[o] = cw[c * 27 + k];
}

// ---------------- A-in-register GEMM: out = A(M x 288) @ Bt(N x 288)^T (+bias) ----------------
// Block = 128 A-rows, 512 thr / 8 waves.  A staged once to LDS (72 KB), each wave
// preloads its 2 m-frags x 9 ks = 18 s16x8 A-frags into VGPRs; the A LDS region is
// then DEAD and is reused as the B double-buffer (2 x 18 KB within the same 72 KB)
// -> LDS stays 72 KB, 2 blocks/CU, 16 waves/CU.
// Main loop per ks: ONE ds_read_b128 (B-frag) + TWO MFMAs  (0.5 reads/MFMA; R4 had 2).
// B staged exactly like proven R4: 18 coalesced ASYNC16/chunk, double-buffered,
// sched_barrier(0), counted vmcnt(8) (8 newest VMEM = this chunk's C-stores) + s_barrier.
// Wave w: n-frag nf = w>>2 (chunk cols nf*16..), m-group mg = w&3 (rows mg*32..mg*32+31).
template <bool BF16OUT, bool ABF16>
__global__ __launch_bounds__(512, 2) void gemm_areg(
    const void* __restrict__ Ax, const u16* __restrict__ Bt,
    const float* __restrict__ bias, void* __restrict__ out, int N) {
  __shared__ __align__(16) u16 lds[36864];  // 73728 B: A-stage, then B dbuf [2][9216 u16]
  const int bm = blockIdx.x * 128;
  const int tid = threadIdx.x;
  const int lane = tid & 63, wave = tid >> 6;
  const int m16 = lane & 15, kq = lane >> 4;
  const int nf = wave >> 2, mg = wave & 3;
  const int NC = N >> 5;                    // 32-col chunks

  // ---- A stage: 128 x 288 bf16 into [72 granules][64 rows][8 u16] ----
  // granule i = g*2 + (row>>6), g = k-octet (0..35); offset(row,g) = g*1024 + (row>>6)*512 + (row&63)*8
  if (ABF16) {
    const u16* Ab = (const u16*)Ax;
    for (int i = wave; i < 72; i += 8) {
      int g = i >> 1, rh = i & 1;
      ASYNC16(Ab + (size_t)(bm + rh * 64 + lane) * 288 + g * 8, &lds[i * 512]);
    }
    asm volatile("s_waitcnt vmcnt(0)" ::: "memory");
  } else {
    const float* Af = (const float*)Ax;
#pragma unroll
    for (int p = 0; p < 18; p++) {          // 9216 float4 / 512 thr
      int s = p * 512 + tid;
      int r = s / 72, q = s - r * 72;       // 72 float4 per row
      float4 v = *(const float4*)(Af + (size_t)(bm + r) * 288 + q * 4);
      u16x4 pk;
      pk[0] = f2bf(v.x); pk[1] = f2bf(v.y); pk[2] = f2bf(v.z); pk[3] = f2bf(v.w);
      *(u16x4*)&lds[(q >> 1) * 1024 + (r >> 6) * 512 + (r & 63) * 8 + (q & 1) * 4] = pk;
    }
  }
  __syncthreads();

  // ---- preload A-frags to registers: rows (mg*2+j)*16+m16, k-octet ks*4+kq ----
  s16x8 areg[2][9];
#pragma unroll
  for (int j = 0; j < 2; j++) {
    const int row = (mg * 2 + j) * 16 + m16;
    const int base = (row >> 6) * 512 + (row & 63) * 8;
#pragma unroll
    for (int ks = 0; ks < 9; ks++)
      areg[j][ks] = *(const s16x8*)&lds[(ks * 4 + kq) * 1024 + base];
  }
  asm volatile("s_waitcnt lgkmcnt(0)" ::: "memory");
  __builtin_amdgcn_s_barrier();             // all waves done reading A before B overwrites

  // ---- B chunk 0 into buf0 ----
  {
    const int r = lane & 31, gh = lane >> 5;
    for (int gp = wave; gp < 18; gp += 8)
      ASYNC16(Bt + (size_t)r * 288 + (gp * 2 + gh) * 8, &lds[gp * 512]);
  }
  asm volatile("s_waitcnt vmcnt(0)" ::: "memory");
  __builtin_amdgcn_s_barrier();

  int buf = 0;
  for (int c = 0; c < NC; c++) {
    // stage next chunk into the other buffer
    if (c + 1 < NC) {
      const u16* Bc = Bt + (size_t)(c + 1) * 32 * 288;
      const int r = lane & 31, gh = lane >> 5;
      u16* bb1 = &lds[(buf ^ 1) * 9216];
      for (int gp = wave; gp < 18; gp += 8)
        ASYNC16(Bc + (size_t)r * 288 + (gp * 2 + gh) * 8, &bb1[gp * 512]);
    }
    __builtin_amdgcn_sched_barrier(0);      // loads strictly precede stores (vmcnt count)

    const u16* bb = &lds[buf * 9216];
    f32x4 acc0 = {0.f, 0.f, 0.f, 0.f}, acc1 = {0.f, 0.f, 0.f, 0.f};
#pragma unroll
    for (int ks = 0; ks < 9; ks++) {
      s16x8 bf = *(const s16x8*)&bb[(ks * 4 + kq) * 256 + (nf * 16 + m16) * 8];
      acc0 = __builtin_amdgcn_mfma_f32_16x16x32_bf16(areg[0][ks], bf, acc0, 0, 0, 0);
      acc1 = __builtin_amdgcn_mfma_f32_16x16x32_bf16(areg[1][ks], bf, acc1, 0, 0, 0);
    }
    // epilogue: D col = m16, rows kq*4+r; j=0 rows mg*32.., j=1 rows mg*32+16..
    const int col = (c << 5) + nf * 16 + m16;
    const size_t r0 = (size_t)(bm + mg * 32 + kq * 4);
    if (BF16OUT) {
      u16* op = (u16*)out;
#pragma unroll
      for (int r = 0; r < 4; r++) {
        op[(r0 + r) * N + col] = f2bf(acc0[r]);
        op[(r0 + 16 + r) * N + col] = f2bf(acc1[r]);
      }
    } else {
      const float bv = bias ? bias[col] : 0.f;
      float* op = (float*)out;
#pragma unroll
      for (int r = 0; r < 4; r++) {
        op[(r0 + r) * N + col] = acc0[r] + bv;
        op[(r0 + 16 + r) * N + col] = acc1[r] + bv;
      }
    }
    if (c + 1 < NC) {
      asm volatile("s_waitcnt vmcnt(8)" ::: "memory");   // 8 newest = my stores; stage loads done
      __builtin_amdgcn_s_barrier();
    }
    buf ^= 1;
  }
}

// ---------------- tiny RPE-bias MLP: (3,63,3) -> (3,63,4) ----------------
__device__ __forceinline__ void ln_relu6(const float* x, float* o,
                                         const float* g, const float* b) {
  float m = 0.f;
#pragma unroll
  for (int i = 0; i < 6; i++) m += x[i];
  m *= (1.f / 6.f);
  float v = 0.f;
#pragma unroll
  for (int i = 0; i < 6; i++) { float d = x[i] - m; v += d * d; }
  v *= (1.f / 6.f);
  float r = rsqrtf(v + 1e-5f);
#pragma unroll
  for (int i = 0; i < 6; i++) {
    float t = (x[i] - m) * r * g[i] + b[i];
    o[i] = t > 0.f ? t : 0.f;
  }
}

__global__ __launch_bounds__(256) void rpe_mlp(
    const float* __restrict__ rpe, const float* __restrict__ pw, const float* __restrict__ pb,
    const float* __restrict__ g1, const float* __restrict__ b1,
    const float* __restrict__ w1, const float* __restrict__ bb1,
    const float* __restrict__ g2, const float* __restrict__ b2,
    const float* __restrict__ w2, const float* __restrict__ bb2,
    const float* __restrict__ g3, const float* __restrict__ b3,
    const float* __restrict__ w3, const float* __restrict__ bb3,
    float* __restrict__ ptab) {
  int t = blockIdx.x * blockDim.x + threadIdx.x;
  if (t >= 3 * 63) return;
  int bi = t / 63, row = t % 63;
  float p[6], q[6];
#pragma unroll
  for (int j = 0; j < 6; j++) {
    float s = pb[bi * 6 + j];
#pragma unroll
    for (int i = 0; i < 3; i++) s += rpe[(bi * 63 + row) * 3 + i] * pw[(bi * 3 + i) * 6 + j];
    p[j] = s;
  }
  ln_relu6(p, q, g1 + bi * 6, b1 + bi * 6);
#pragma unroll
  for (int j = 0; j < 6; j++) {
    float s = bb1[bi * 6 + j];
#pragma unroll
    for (int i = 0; i < 6; i++) s += q[i] * w1[(bi * 6 + i) * 6 + j];
    p[j] = s;
  }
  ln_relu6(p, q, g2 + bi * 6, b2 + bi * 6);
#pragma unroll
  for (int j = 0; j < 6; j++) {
    float s = bb2[bi * 6 + j];
#pragma unroll
    for (int i = 0; i < 6; i++) s += q[i] * w2[(bi * 6 + i) * 6 + j];
    p[j] = s;
  }
  ln_relu6(p, q, g3 + bi * 6, b3 + bi * 6);
#pragma unroll
  for (int h = 0; h < 4; h++) {
    float s = bb3[bi * 4 + h];
#pragma unroll
    for (int i = 0; i < 6; i++) s += q[i] * w3[(bi * 6 + i) * 4 + h];
    ptab[(bi * 63 + row) * 4 + h] = s;
  }
}

// ---------------- windowed attention via MFMA: 4 windows per 256-thr block ----------------
// One wave per window, fully independent (private LDS slices, ZERO barriers).
// Per (window, head): score = mfma(Qfrag,Kfrag) [K=32, ch24..31 zero]; quad-wide
// softmax via shfl_xor; P stored hi+lo bf16 in k=0..15/16..31 against duplicated
// V^T cols -> ~f32-precision PV at no extra MFMA cost.
__global__ __launch_bounds__(256) void attn_kernel(
    const u16* __restrict__ qkv, const float* __restrict__ ptab,
    const int* __restrict__ rel, float* __restrict__ y) {
  __shared__ __align__(16) u16 sq[4][640];     // [n][40]: k 0..23 data, 24..31 zero
  __shared__ __align__(16) u16 sk[4][640];
  __shared__ __align__(16) u16 svt[4][1280];   // [ch][40]: cols 0..15 V^T, 16..31 dup; rows 24..31 zero
  __shared__ __align__(16) u16 sps[4][640];    // [n][40]: m 0..15 hi, 16..31 lo

  const int bi = blockIdx.y;
  const int wsh = (bi == 2) ? 1 : 2;            // log2(Wsp)
  const int hsh = (bi == 2) ? 2 : 1;            // log2(Hsp)
  const int Wm1 = (1 << wsh) - 1, Hm1 = (1 << hsh) - 1;
  const int nW = RES >> wsh, nH = RES >> hsh;
  const int tid = threadIdx.x;
  const int wv = tid >> 6, lane = tid & 63;
  const int wid = blockIdx.x * 4 + wv;          // 0..4095
  const int b = wid >> 11;
  const int r_ = wid & 2047;
  const int w0 = r_ % nW;
  const int r2 = r_ / nW;
  const int h0 = r2 % nH;
  const int d0 = r2 / nH;

  u16* q_  = sq[wv];
  u16* k_  = sk[wv];
  u16* vt_ = svt[wv];
  u16* ps_ = sps[wv];
  const int m16 = lane & 15, q4 = lane >> 4;

  // ---- zero ONLY the pad regions (never rewritten by staging) ----
  {
    uint4 z = make_uint4(0u, 0u, 0u, 0u);
    if (lane < 16) {
      *(uint4*)&q_[lane * 40 + 24] = z;
      *(uint4*)&k_[lane * 40 + 24] = z;
    }
    if (lane < 40) {                      // svt rows 24..31, full 40-u16 rows
      int row = 24 + lane / 5, ch = (lane % 5) * 8;
      *(uint4*)&vt_[row * 40 + ch] = z;
    }
  }

  // rel gather (head-invariant): rv[r] for n = q4*4+r, m = m16
  int rv[4];
#pragma unroll
  for (int r = 0; r < 4; r++) rv[r] = rel[(bi * 16 + q4 * 4 + r) * 16 + m16];

  // per-row global y bases for n = q4*4+r
  size_t ybase[4];
#pragma unroll
  for (int r = 0; r < 4; r++) {
    int n = q4 * 4 + r;
    int dd = n >> 3, hh2 = (n >> wsh) & Hm1, ww = n & Wm1;
    int l = ((d0 * 2 + dd) * RES + ((h0 << hsh) + hh2)) * RES + ((w0 << wsh) + ww);
    ybase[r] = (size_t)(b * LTOK + l) * CDIM + bi * 96;
  }

  const float scale = 0.20412414523193154f;  // 1/sqrt(24)

  for (int hd = 0; hd < 4; hd++) {
    // ---- stage q,k,v: 16 tokens x 24 ch in 16B chunks (3 per token per array) ----
    if (lane < 48) {
      int n = lane / 3, ch = (lane % 3) * 8;
      int dd = n >> 3, hh2 = (n >> wsh) & Hm1, ww = n & Wm1;
      int l = ((d0 * 2 + dd) * RES + ((h0 << hsh) + hh2)) * RES + ((w0 << wsh) + ww);
      size_t base = (size_t)(b * LTOK + l) * NQKV + bi * 96 + hd * 24 + ch;
      uint4 qv = *(const uint4*)(qkv + base);
      uint4 kv = *(const uint4*)(qkv + base + 288);
      uint4 vv = *(const uint4*)(qkv + base + 576);
      *(uint4*)&q_[n * 40 + ch] = qv;
      *(uint4*)&k_[n * 40 + ch] = kv;
      const u16* vp = (const u16*)&vv;
#pragma unroll
      for (int j = 0; j < 8; j++) {
        vt_[(ch + j) * 40 + n] = vp[j];
        vt_[(ch + j) * 40 + 16 + n] = vp[j];
      }
    }

    // ---- scores: one MFMA (D: col=m16 -> key m, rows q4*4+r -> query n) ----
    s16x8 af = *(const s16x8*)&q_[m16 * 40 + q4 * 8];
    s16x8 bf = *(const s16x8*)&k_[m16 * 40 + q4 * 8];
    f32x4 sc = __builtin_amdgcn_mfma_f32_16x16x32_bf16(af, bf, (f32x4){0.f, 0.f, 0.f, 0.f}, 0, 0, 0);

    float inv[4];
#pragma unroll
    for (int r = 0; r < 4; r++) {
      float s = sc[r] * scale + ptab[(size_t)(bi * 63 + rv[r]) * 4 + hd];
      float mx = s;
#pragma unroll
      for (int msk = 1; msk <= 8; msk <<= 1) mx = fmaxf(mx, __shfl_xor(mx, msk));
      float e = expf(s - mx);
      float sum = e;
#pragma unroll
      for (int msk = 1; msk <= 8; msk <<= 1) sum += __shfl_xor(sum, msk);
      inv[r] = 1.f / sum;
      u16 hi = f2bf(e);
      float lo = e - bf2f(hi);
      ps_[(q4 * 4 + r) * 40 + m16] = hi;
      ps_[(q4 * 4 + r) * 40 + 16 + m16] = f2bf(lo);
    }

    // ---- PV: 2 MFMAs (A = P hi|lo over k=0..31; B = svt rows ch, ch+16) ----
    s16x8 pa = *(const s16x8*)&ps_[m16 * 40 + q4 * 8];
    s16x8 v1 = *(const s16x8*)&vt_[m16 * 40 + q4 * 8];
    s16x8 v2 = *(const s16x8*)&vt_[(16 + m16) * 40 + q4 * 8];
    f32x4 o1 = __builtin_amdgcn_mfma_f32_16x16x32_bf16(pa, v1, (f32x4){0.f, 0.f, 0.f, 0.f}, 0, 0, 0);
    f32x4 o2 = __builtin_amdgcn_mfma_f32_16x16x32_bf16(pa, v2, (f32x4){0.f, 0.f, 0.f, 0.f}, 0, 0, 0);

#pragma unroll
    for (int r = 0; r < 4; r++) {
      float* yp = y + ybase[r] + hd * 24;
      yp[m16] = o1[r] * inv[r];
      if (m16 < 8) yp[16 + m16] = o2[r] * inv[r];
    }
  }
}

// ---------------- depthwise 3x3x3 conv on V (bf16) ----------------
// one block = 8x8x8 token tile x 32 channels, 512 threads (1 token/thread).
// Halo 10^3 tokens staged bf16, token stride 40 u16 (80 B, conflict-free spread).
// Weights k-major [27][288]: 32 contiguous floats per tap (uniform s_loads).
template <bool BF16OUT>
__global__ __launch_bounds__(512, 4) void conv_tile_kernel(
    const u16* __restrict__ qkv, const float* __restrict__ wck,
    const float* __restrict__ cb, float* __restrict__ y, u16* __restrict__ ybf) {
  __shared__ __align__(16) u16 vs[1000 * 40];   // 80000 B
  const int tid = threadIdx.x;
  const int bx = blockIdx.x;           // 0..127 : b*64 + tile
  const int c0 = blockIdx.y * 32;      // channel group 0..8
  const int b = bx >> 6;
  const int t = bx & 63;
  const int td = (t >> 4) * 8, th = ((t >> 2) & 3) * 8, tw = (t & 3) * 8;

  // ---- stage V halo tile (10x10x10 tokens x 32 ch bf16) ----
#pragma unroll
  for (int p = 0; p < 8; p++) {
    int idx = p * 512 + tid;           // 4 chunks of 16B per token
    if (idx < 4000) {
      int tok = idx >> 2, chunk = idx & 3;
      int dz = tok / 100, rem = tok - dz * 100;
      int hz = rem / 10, wz = rem - hz * 10;
      int d = td + dz - 1, h = th + hz - 1, w = tw + wz - 1;
      uint4 v = make_uint4(0u, 0u, 0u, 0u);
      if ((unsigned)d < 32u && (unsigned)h < 32u && (unsigned)w < 32u)
        v = *(const uint4*)(qkv +
              ((size_t)(b * LTOK + ((d * 32 + h) * 32 + w))) * NQKV + 576 + c0 + chunk * 8);
      *(uint4*)&vs[tok * 40 + chunk * 8] = v;
    }
  }
  __syncthreads();

  // ---- compute: thread owns token (d,h,w) ----
  const int d = tid >> 6, h = (tid >> 3) & 7, w = tid & 7;
  float acc[32];
#pragma unroll
  for (int c = 0; c < 32; c++) acc[c] = cb[c0 + c];

  for (int kd = 0; kd < 3; kd++) {
#pragma unroll
    for (int kh = 0; kh < 3; kh++) {
#pragma unroll
      for (int kw = 0; kw < 3; kw++) {
        const int k = kd * 9 + kh * 3 + kw;
        const float* wk = wck + k * 288 + c0;   // 32 contiguous uniform floats
        const u16* p0 = &vs[(((d + kd) * 100 + (h + kh) * 10) + (w + kw)) * 40];
#pragma unroll
        for (int cq = 0; cq < 4; cq++) {
          uint4 v0 = *(const uint4*)(p0 + cq * 8);
          const unsigned* u0 = (const unsigned*)&v0;
#pragma unroll
          for (int j = 0; j < 4; j++) {
            const int ce = cq * 8 + j * 2;
            acc[ce]     += bflo(u0[j]) * wk[ce];
            acc[ce + 1] += bfhi(u0[j]) * wk[ce + 1];
          }
        }
      }
    }
  }

  const int tt = b * LTOK + ((td + d) * 32 + (th + h)) * 32 + (tw + w);

  if (BF16OUT) {
    const float4* yp = (const float4*)&y[(size_t)tt * CDIM + c0];
    unsigned pk[16];
#pragma unroll
    for (int q = 0; q < 8; q++) {
      float4 cur = yp[q];
      float va = cur.x + acc[q * 4],     vb = cur.y + acc[q * 4 + 1];
      float vc = cur.z + acc[q * 4 + 2], vd = cur.w + acc[q * 4 + 3];
      pk[q * 2]     = (unsigned)f2bf(va) | ((unsigned)f2bf(vb) << 16);
      pk[q * 2 + 1] = (unsigned)f2bf(vc) | ((unsigned)f2bf(vd) << 16);
    }
    uint4* op = (uint4*)(ybf + (size_t)tt * CDIM + c0);
#pragma unroll
    for (int q = 0; q < 4; q++) op[q] = ((const uint4*)pk)[q];
  } else {
    float4* yp = (float4*)&y[(size_t)tt * CDIM + c0];
#pragma unroll
    for (int q = 0; q < 8; q++) {
      float4 cur = yp[q];
      cur.x += acc[q * 4];     cur.y += acc[q * 4 + 1];
      cur.z += acc[q * 4 + 2]; cur.w += acc[q * 4 + 3];
      yp[q] = cur;
    }
  }
}

extern "C" void kernel_launch(void* const* d_in, const int* in_sizes, int n_in,
                              void* d_out, int out_size, void* d_ws, size_t ws_size,
                              hipStream_t stream) {
  const float* x      = (const float*)d_in[0];
  // d_in[1..3] = D,H,W scalars (fixed 32)
  const float* w_qkv  = (const float*)d_in[4];
  const float* w_proj = (const float*)d_in[5];
  const float* b_proj = (const float*)d_in[6];
  const float* conv_w = (const float*)d_in[7];
  const float* conv_b = (const float*)d_in[8];
  const float* pos_w  = (const float*)d_in[9];
  const float* pos_b  = (const float*)d_in[10];
  const float* ln1_g  = (const float*)d_in[11];
  const float* ln1_b  = (const float*)d_in[12];
  const float* lin1_w = (const float*)d_in[13];
  const float* lin1_b = (const float*)d_in[14];
  const float* ln2_g  = (const float*)d_in[15];
  const float* ln2_b  = (const float*)d_in[16];
  const float* lin2_w = (const float*)d_in[17];
  const float* lin2_b = (const float*)d_in[18];
  const float* ln3_g  = (const float*)d_in[19];
  const float* ln3_b  = (const float*)d_in[20];
  const float* lin3_w = (const float*)d_in[21];
  const float* lin3_b = (const float*)d_in[22];
  const float* rpe    = (const float*)d_in[23];
  const int*   rel    = (const int*)d_in[24];
  float* out = (float*)d_out;

  // ws layout:
  //   [0, Q)         qkv (bf16), Q = 65536*864*2  -- dead after conv
  //   [Q, +497664)   wqt: w_qkv^T bf16 (864 x 288)
  //   [.., +165888)  wpt: w_proj^T bf16 (288 x 288)
  //   [.., +3024)    ptab f32
  //   [.., +31104)   wck f32 (conv weights k-major)
  //   big path: ybf bf16 (37.7 MB) -> conv writes bf16, proj GEMM ASYNC16-A path
  //   fallback: conv RMW f32 on d_out; proj GEMM in-place d_out->d_out
  //             (safe: A fully in regs before first store of the block's own rows)
  const size_t Q = (size_t)MROWS * NQKV * sizeof(u16);
  u16* qkv   = (u16*)d_ws;
  u16* wqt   = (u16*)((char*)d_ws + Q);
  u16* wpt   = (u16*)((char*)d_ws + Q + 497664);
  float* ptab  = (float*)((char*)d_ws + Q + 497664 + 165888);
  float* wck   = (float*)((char*)d_ws + Q + 497664 + 165888 + 3024);

  const size_t yoff = (Q + 497664 + 165888 + 3024 + 31104 + 255) & ~(size_t)255;
  const size_t ybf_bytes = (size_t)MROWS * CDIM * sizeof(u16);
  const bool big = ws_size >= yoff + ybf_bytes;
  u16* ybf = (u16*)((char*)d_ws + yoff);

  // 0. weight transforms (tiny)
  transpose_cvt<<<(NQKV * CDIM + 255) / 256, 256, 0, stream>>>(w_qkv, wqt, CDIM, NQKV);
  transpose_cvt<<<(CDIM * CDIM + 255) / 256, 256, 0, stream>>>(w_proj, wpt, CDIM, CDIM);
  conv_w_kmajor<<<(27 * 288 + 255) / 256, 256, 0, stream>>>(conv_w, wck);
  // 1. qkv = bf16(x @ w_qkv)   (A-in-reg, 512 blocks x 512 thr)
  gemm_areg<true, false><<<MROWS / 128, 512, 0, stream>>>(x, wqt, nullptr, qkv, NQKV);
  // 2. rpe bias tables (tiny)
  rpe_mlp<<<1, 256, 0, stream>>>(rpe, pos_w, pos_b, ln1_g, ln1_b, lin1_w, lin1_b,
                                 ln2_g, ln2_b, lin2_w, lin2_b, ln3_g, ln3_b,
                                 lin3_w, lin3_b, ptab);
  // 3. windowed attention (MFMA) -> d_out (f32, fully overwritten)
  attn_kernel<<<dim3(1024, 3), 256, 0, stream>>>(qkv, ptab, rel, out);
  // 4+5. conv add + projection
  if (big) {
    conv_tile_kernel<true><<<dim3(128, 9), 512, 0, stream>>>(qkv, wck, conv_b, out, ybf);
    gemm_areg<false, true><<<MROWS / 128, 512, 0, stream>>>(ybf, wpt, b_proj, out, CDIM);
  } else {
    conv_tile_kernel<false><<<dim3(128, 9), 512, 0, stream>>>(qkv, wck, conv_b, out, nullptr);
    gemm_areg<false, false><<<MROWS / 128, 512, 0, stream>>>(out, wpt, b_proj, out, CDIM);
  }
}

// Round 8
// 362.193 us; speedup vs baseline: 1.7114x; 1.0818x over previous
//
#include <hip/hip_runtime.h>
#include <hip/hip_bf16.h>
#include <math.h>

#define BATCH 2
#define RES   32
#define LTOK  32768          // RES^3
#define CDIM  288
#define NQKV  864
#define MROWS 65536          // BATCH*LTOK

typedef unsigned short u16;
typedef u16   u16x4 __attribute__((ext_vector_type(4)));
typedef short s16x8 __attribute__((ext_vector_type(8)));   // 8 bf16 in 4 VGPRs (MFMA A/B frag)
typedef float f32x4 __attribute__((ext_vector_type(4)));   // MFMA C/D frag

__device__ __forceinline__ u16 f2bf(float f) {
  union { __hip_bfloat16 h; u16 u; } x;
  x.h = __float2bfloat16(f);
  return x.u;
}
__device__ __forceinline__ float bf2f(u16 u) {
  union { u16 u; __hip_bfloat16 h; } x;
  x.u = u;
  return __bfloat162float(x.h);
}
// bf16 pair unpack from packed u32 (lo = even channel, hi = odd channel)
__device__ __forceinline__ float bflo(unsigned u) {
  union { unsigned u; float f; } x; x.u = u << 16; return x.f;
}
__device__ __forceinline__ float bfhi(unsigned u) {
  union { unsigned u; float f; } x; x.u = u & 0xffff0000u; return x.f;
}

// async 16B global->LDS copy (per-lane global src, wave-uniform LDS base + lane*16)
#define ASYNC16(gsrc, ldst)                                                        \
  __builtin_amdgcn_global_load_lds(                                                \
      (const __attribute__((address_space(1))) void*)(gsrc),                       \
      (__attribute__((address_space(3))) void*)(ldst), 16, 0, 0)

// ---------------- weight transpose+convert: W (K x N) f32 -> Wt (N x K) bf16 ----------------
__global__ __launch_bounds__(256) void transpose_cvt(
    const float* __restrict__ w, u16* __restrict__ wt, int K, int N) {
  int o = blockIdx.x * 256 + threadIdx.x;
  if (o >= N * K) return;
  int n = o / K, k = o - n * K;
  wt[o] = f2bf(w[(size_t)k * N + n]);
}

// conv weights (C,1,3,3,3) -> k-major [27][288]
__global__ __launch_bounds__(256) void conv_w_kmajor(
    const float* __restrict__ cw, float* __restrict__ wck) {
  int o = blockIdx.x * 256 + threadIdx.x;
  if (o >= 27 * 288) return;
  int k = o / 288, c = o - k * 288;
  wck[o] = cw[c * 27 + k];
}

// ---------------- A-in-register GEMM: out = A(M x 288) @ Bt(N x 288)^T (+bias) ----------------
// (unchanged from R7 -- verified 392us config)
template <bool BF16OUT, bool ABF16>
__global__ __launch_bounds__(512, 2) void gemm_areg(
    const void* __restrict__ Ax, const u16* __restrict__ Bt,
    const float* __restrict__ bias, void* __restrict__ out, int N) {
  __shared__ __align__(16) u16 lds[36864];  // 73728 B: A-stage, then B dbuf [2][9216 u16]
  const int bm = blockIdx.x * 128;
  const int tid = threadIdx.x;
  const int lane = tid & 63, wave = tid >> 6;
  const int m16 = lane & 15, kq = lane >> 4;
  const int nf = wave >> 2, mg = wave & 3;
  const int NC = N >> 5;                    // 32-col chunks

  if (ABF16) {
    const u16* Ab = (const u16*)Ax;
    for (int i = wave; i < 72; i += 8) {
      int g = i >> 1, rh = i & 1;
      ASYNC16(Ab + (size_t)(bm + rh * 64 + lane) * 288 + g * 8, &lds[i * 512]);
    }
    asm volatile("s_waitcnt vmcnt(0)" ::: "memory");
  } else {
    const float* Af = (const float*)Ax;
#pragma unroll
    for (int p = 0; p < 18; p++) {          // 9216 float4 / 512 thr
      int s = p * 512 + tid;
      int r = s / 72, q = s - r * 72;       // 72 float4 per row
      float4 v = *(const float4*)(Af + (size_t)(bm + r) * 288 + q * 4);
      u16x4 pk;
      pk[0] = f2bf(v.x); pk[1] = f2bf(v.y); pk[2] = f2bf(v.z); pk[3] = f2bf(v.w);
      *(u16x4*)&lds[(q >> 1) * 1024 + (r >> 6) * 512 + (r & 63) * 8 + (q & 1) * 4] = pk;
    }
  }
  __syncthreads();

  s16x8 areg[2][9];
#pragma unroll
  for (int j = 0; j < 2; j++) {
    const int row = (mg * 2 + j) * 16 + m16;
    const int base = (row >> 6) * 512 + (row & 63) * 8;
#pragma unroll
    for (int ks = 0; ks < 9; ks++)
      areg[j][ks] = *(const s16x8*)&lds[(ks * 4 + kq) * 1024 + base];
  }
  asm volatile("s_waitcnt lgkmcnt(0)" ::: "memory");
  __builtin_amdgcn_s_barrier();             // all waves done reading A before B overwrites

  {
    const int r = lane & 31, gh = lane >> 5;
    for (int gp = wave; gp < 18; gp += 8)
      ASYNC16(Bt + (size_t)r * 288 + (gp * 2 + gh) * 8, &lds[gp * 512]);
  }
  asm volatile("s_waitcnt vmcnt(0)" ::: "memory");
  __builtin_amdgcn_s_barrier();

  int buf = 0;
  for (int c = 0; c < NC; c++) {
    if (c + 1 < NC) {
      const u16* Bc = Bt + (size_t)(c + 1) * 32 * 288;
      const int r = lane & 31, gh = lane >> 5;
      u16* bb1 = &lds[(buf ^ 1) * 9216];
      for (int gp = wave; gp < 18; gp += 8)
        ASYNC16(Bc + (size_t)r * 288 + (gp * 2 + gh) * 8, &bb1[gp * 512]);
    }
    __builtin_amdgcn_sched_barrier(0);      // loads strictly precede stores (vmcnt count)

    const u16* bb = &lds[buf * 9216];
    f32x4 acc0 = {0.f, 0.f, 0.f, 0.f}, acc1 = {0.f, 0.f, 0.f, 0.f};
#pragma unroll
    for (int ks = 0; ks < 9; ks++) {
      s16x8 bf = *(const s16x8*)&bb[(ks * 4 + kq) * 256 + (nf * 16 + m16) * 8];
      acc0 = __builtin_amdgcn_mfma_f32_16x16x32_bf16(areg[0][ks], bf, acc0, 0, 0, 0);
      acc1 = __builtin_amdgcn_mfma_f32_16x16x32_bf16(areg[1][ks], bf, acc1, 0, 0, 0);
    }
    const int col = (c << 5) + nf * 16 + m16;
    const size_t r0 = (size_t)(bm + mg * 32 + kq * 4);
    if (BF16OUT) {
      u16* op = (u16*)out;
#pragma unroll
      for (int r = 0; r < 4; r++) {
        op[(r0 + r) * N + col] = f2bf(acc0[r]);
        op[(r0 + 16 + r) * N + col] = f2bf(acc1[r]);
      }
    } else {
      const float bv = bias ? bias[col] : 0.f;
      float* op = (float*)out;
#pragma unroll
      for (int r = 0; r < 4; r++) {
        op[(r0 + r) * N + col] = acc0[r] + bv;
        op[(r0 + 16 + r) * N + col] = acc1[r] + bv;
      }
    }
    if (c + 1 < NC) {
      asm volatile("s_waitcnt vmcnt(8)" ::: "memory");   // 8 newest = my stores; stage loads done
      __builtin_amdgcn_s_barrier();
    }
    buf ^= 1;
  }
}

// ---------------- tiny RPE-bias MLP: (3,63,3) -> (3,63,4) ----------------
__device__ __forceinline__ void ln_relu6(const float* x, float* o,
                                         const float* g, const float* b) {
  float m = 0.f;
#pragma unroll
  for (int i = 0; i < 6; i++) m += x[i];
  m *= (1.f / 6.f);
  float v = 0.f;
#pragma unroll
  for (int i = 0; i < 6; i++) { float d = x[i] - m; v += d * d; }
  v *= (1.f / 6.f);
  float r = rsqrtf(v + 1e-5f);
#pragma unroll
  for (int i = 0; i < 6; i++) {
    float t = (x[i] - m) * r * g[i] + b[i];
    o[i] = t > 0.f ? t : 0.f;
  }
}

__global__ __launch_bounds__(256) void rpe_mlp(
    const float* __restrict__ rpe, const float* __restrict__ pw, const float* __restrict__ pb,
    const float* __restrict__ g1, const float* __restrict__ b1,
    const float* __restrict__ w1, const float* __restrict__ bb1,
    const float* __restrict__ g2, const float* __restrict__ b2,
    const float* __restrict__ w2, const float* __restrict__ bb2,
    const float* __restrict__ g3, const float* __restrict__ b3,
    const float* __restrict__ w3, const float* __restrict__ bb3,
    float* __restrict__ ptab) {
  int t = blockIdx.x * blockDim.x + threadIdx.x;
  if (t >= 3 * 63) return;
  int bi = t / 63, row = t % 63;
  float p[6], q[6];
#pragma unroll
  for (int j = 0; j < 6; j++) {
    float s = pb[bi * 6 + j];
#pragma unroll
    for (int i = 0; i < 3; i++) s += rpe[(bi * 63 + row) * 3 + i] * pw[(bi * 3 + i) * 6 + j];
    p[j] = s;
  }
  ln_relu6(p, q, g1 + bi * 6, b1 + bi * 6);
#pragma unroll
  for (int j = 0; j < 6; j++) {
    float s = bb1[bi * 6 + j];
#pragma unroll
    for (int i = 0; i < 6; i++) s += q[i] * w1[(bi * 6 + i) * 6 + j];
    p[j] = s;
  }
  ln_relu6(p, q, g2 + bi * 6, b2 + bi * 6);
#pragma unroll
  for (int j = 0; j < 6; j++) {
    float s = bb2[bi * 6 + j];
#pragma unroll
    for (int i = 0; i < 6; i++) s += q[i] * w2[(bi * 6 + i) * 6 + j];
    p[j] = s;
  }
  ln_relu6(p, q, g3 + bi * 6, b3 + bi * 6);
#pragma unroll
  for (int h = 0; h < 4; h++) {
    float s = bb3[bi * 4 + h];
#pragma unroll
    for (int i = 0; i < 6; i++) s += q[i] * w3[(bi * 6 + i) * 4 + h];
    ptab[(bi * 63 + row) * 4 + h] = s;
  }
}

// ---------------- windowed attention via MFMA: 4 windows per 256-thr block ----------------
// Latency-chain optimized (R8):
//  - software-pipelined head loop: head h+1's q/k/v global loads issued before head h compute
//  - no max-subtraction (|s| <= ~0.7 by construction: 0.02-scaled weights) -> no max reduce
//  - softmax denominator FREE from PV: V channel 24 holds 1.0 (was zero pad) -> o2 at
//    e=24 is the exact sum of the quantized P used in the numerator; 1 broadcast shfl
//  - V stored in natural [m][e] layout (vector store); PV B-frags assembled via 16
//    conflict-free scalar u16 reads (kills the 4.7M-conflict transpose writes)
//  - ptab rows prefetched as 4x float4 before the loop
//  - BF16OUT: writes bf16 att into ybf (conv RMWs it in place)
// LDS 4 windows x 4 arrays x [16][40] u16 = 20.5 KB/block. Zero barriers (1 wave/window).
template <bool BF16OUT>
__global__ __launch_bounds__(256) void attn_kernel(
    const u16* __restrict__ qkv, const float* __restrict__ ptab,
    const int* __restrict__ rel, float* __restrict__ y, u16* __restrict__ ybf) {
  __shared__ __align__(16) u16 sq[4][640];     // [n][40]: k 0..23 data, 24..31 zero
  __shared__ __align__(16) u16 sk[4][640];
  __shared__ __align__(16) u16 sv[4][640];     // [m][40]: e 0..23 data, e24 = 1.0, 25..31 zero
  __shared__ __align__(16) u16 sps[4][640];    // [n][40]: m 0..15 hi, 16..31 lo

  const int bi = blockIdx.y;
  const int wsh = (bi == 2) ? 1 : 2;            // log2(Wsp)
  const int hsh = (bi == 2) ? 2 : 1;            // log2(Hsp)
  const int Wm1 = (1 << wsh) - 1, Hm1 = (1 << hsh) - 1;
  const int nW = RES >> wsh, nH = RES >> hsh;
  const int tid = threadIdx.x;
  const int wv = tid >> 6, lane = tid & 63;
  const int wid = blockIdx.x * 4 + wv;          // 0..4095
  const int b = wid >> 11;
  const int r_ = wid & 2047;
  const int w0 = r_ % nW;
  const int r2 = r_ / nW;
  const int h0 = r2 % nH;
  const int d0 = r2 / nH;

  u16* q_  = sq[wv];
  u16* k_  = sk[wv];
  u16* v_  = sv[wv];
  u16* ps_ = sps[wv];
  const int m16 = lane & 15, q4 = lane >> 4;

  // ---- pads: q/k cols 24..31 zero; v cols 24..31 = {1.0, 0...} (sum column at e=24) ----
  if (lane < 16) {
    uint4 z = make_uint4(0u, 0u, 0u, 0u);
    *(uint4*)&q_[lane * 40 + 24] = z;
    *(uint4*)&k_[lane * 40 + 24] = z;
    *(uint4*)&v_[lane * 40 + 24] = make_uint4(0x3f80u, 0u, 0u, 0u);  // bf16(1.0) at e=24
  }

  // rel gather + ptab prefetch (head-invariant rows, 4 consecutive floats per row)
  float4 pt[4];
#pragma unroll
  for (int r = 0; r < 4; r++) {
    int rv = rel[(bi * 16 + q4 * 4 + r) * 16 + m16];
    pt[r] = *(const float4*)&ptab[(size_t)(bi * 63 + rv) * 4];
  }

  // per-row output bases for n = q4*4+r (element index, valid for f32 y and u16 ybf)
  size_t ybase[4];
#pragma unroll
  for (int r = 0; r < 4; r++) {
    int n = q4 * 4 + r;
    int dd = n >> 3, hh2 = (n >> wsh) & Hm1, ww = n & Wm1;
    int l = ((d0 * 2 + dd) * RES + ((h0 << hsh) + hh2)) * RES + ((w0 << wsh) + ww);
    ybase[r] = (size_t)(b * LTOK + l) * CDIM + bi * 96;
  }

  // staging geometry (lane < 48): token sn, 8-ch chunk sc
  const int sn = lane / 3, sc = (lane % 3) * 8;
  size_t sbase = 0;
  if (lane < 48) {
    int dd = sn >> 3, hh2 = (sn >> wsh) & Hm1, ww = sn & Wm1;
    int l = ((d0 * 2 + dd) * RES + ((h0 << hsh) + hh2)) * RES + ((w0 << wsh) + ww);
    sbase = (size_t)(b * LTOK + l) * NQKV + bi * 96 + sc;
  }

  const float scale = 0.20412414523193154f;  // 1/sqrt(24)

  // prefetch head 0
  uint4 pq, pk, pv;
  if (lane < 48) {
    pq = *(const uint4*)(qkv + sbase);
    pk = *(const uint4*)(qkv + sbase + 288);
    pv = *(const uint4*)(qkv + sbase + 576);
  }

#pragma unroll
  for (int hd = 0; hd < 4; hd++) {
    // stage current head to LDS (vector stores; v natural [m][e])
    if (lane < 48) {
      *(uint4*)&q_[sn * 40 + sc] = pq;
      *(uint4*)&k_[sn * 40 + sc] = pk;
      *(uint4*)&v_[sn * 40 + sc] = pv;
    }
    // prefetch next head (latency hides under this head's compute)
    if (hd < 3 && lane < 48) {
      size_t nb = sbase + (size_t)(hd + 1) * 24;
      pq = *(const uint4*)(qkv + nb);
      pk = *(const uint4*)(qkv + nb + 288);
      pv = *(const uint4*)(qkv + nb + 576);
    }

    // ---- scores: one MFMA (D: col=m16 -> key m, rows q4*4+r -> query n) ----
    s16x8 af = *(const s16x8*)&q_[m16 * 40 + q4 * 8];
    s16x8 bf = *(const s16x8*)&k_[m16 * 40 + q4 * 8];
    f32x4 sc_ = __builtin_amdgcn_mfma_f32_16x16x32_bf16(af, bf, (f32x4){0.f, 0.f, 0.f, 0.f}, 0, 0, 0);

#pragma unroll
    for (int r = 0; r < 4; r++) {
      const float* ptr4 = (const float*)&pt[r];
      float s = sc_[r] * scale + ptr4[hd];
      float e = expf(s);                       // |s| <= ~0.7: no max subtraction needed
      u16 hi = f2bf(e);
      float lo = e - bf2f(hi);
      ps_[(q4 * 4 + r) * 40 + m16] = hi;
      ps_[(q4 * 4 + r) * 40 + 16 + m16] = f2bf(lo);
    }

    // ---- PV: 2 MFMAs; B-frags assembled from natural V via scalar reads ----
    s16x8 pa = *(const s16x8*)&ps_[m16 * 40 + q4 * 8];
    s16x8 v1, v2;
    const int mrow = (q4 & 1) * 8;
#pragma unroll
    for (int j = 0; j < 8; j++) {
      v1[j] = (short)v_[(mrow + j) * 40 + m16];          // e = m16       (0..15)
      v2[j] = (short)v_[(mrow + j) * 40 + 16 + m16];     // e = 16 + m16  (16..31; 24=ones)
    }
    f32x4 o1 = __builtin_amdgcn_mfma_f32_16x16x32_bf16(pa, v1, (f32x4){0.f, 0.f, 0.f, 0.f}, 0, 0, 0);
    f32x4 o2 = __builtin_amdgcn_mfma_f32_16x16x32_bf16(pa, v2, (f32x4){0.f, 0.f, 0.f, 0.f}, 0, 0, 0);

#pragma unroll
    for (int r = 0; r < 4; r++) {
      float sum = __shfl(o2[r], (lane & 48) + 8);        // e=24 ones-column = denominator
      float inv = 1.f / sum;
      if (BF16OUT) {
        u16* yp = ybf + ybase[r] + hd * 24;
        yp[m16] = f2bf(o1[r] * inv);
        if (m16 < 8) yp[16 + m16] = f2bf(o2[r] * inv);
      } else {
        float* yp = y + ybase[r] + hd * 24;
        yp[m16] = o1[r] * inv;
        if (m16 < 8) yp[16 + m16] = o2[r] * inv;
      }
    }
  }
}

// ---------------- depthwise 3x3x3 conv on V (bf16) ----------------
// one block = 8x8x8 token tile x 32 channels, 512 threads (1 token/thread).
// BF16OUT: in-place RMW on ybf (bf16 att written by attn) -- halves y read traffic.
template <bool BF16OUT>
__global__ __launch_bounds__(512, 4) void conv_tile_kernel(
    const u16* __restrict__ qkv, const float* __restrict__ wck,
    const float* __restrict__ cb, float* __restrict__ y, u16* __restrict__ ybf) {
  __shared__ __align__(16) u16 vs[1000 * 40];   // 80000 B
  const int tid = threadIdx.x;
  const int bx = blockIdx.x;           // 0..127 : b*64 + tile
  const int c0 = blockIdx.y * 32;      // channel group 0..8
  const int b = bx >> 6;
  const int t = bx & 63;
  const int td = (t >> 4) * 8, th = ((t >> 2) & 3) * 8, tw = (t & 3) * 8;

  // ---- stage V halo tile (10x10x10 tokens x 32 ch bf16) ----
#pragma unroll
  for (int p = 0; p < 8; p++) {
    int idx = p * 512 + tid;           // 4 chunks of 16B per token
    if (idx < 4000) {
      int tok = idx >> 2, chunk = idx & 3;
      int dz = tok / 100, rem = tok - dz * 100;
      int hz = rem / 10, wz = rem - hz * 10;
      int d = td + dz - 1, h = th + hz - 1, w = tw + wz - 1;
      uint4 v = make_uint4(0u, 0u, 0u, 0u);
      if ((unsigned)d < 32u && (unsigned)h < 32u && (unsigned)w < 32u)
        v = *(const uint4*)(qkv +
              ((size_t)(b * LTOK + ((d * 32 + h) * 32 + w))) * NQKV + 576 + c0 + chunk * 8);
      *(uint4*)&vs[tok * 40 + chunk * 8] = v;
    }
  }
  __syncthreads();

  // ---- compute: thread owns token (d,h,w) ----
  const int d = tid >> 6, h = (tid >> 3) & 7, w = tid & 7;
  float acc[32];
#pragma unroll
  for (int c = 0; c < 32; c++) acc[c] = cb[c0 + c];

  for (int kd = 0; kd < 3; kd++) {
#pragma unroll
    for (int kh = 0; kh < 3; kh++) {
#pragma unroll
      for (int kw = 0; kw < 3; kw++) {
        const int k = kd * 9 + kh * 3 + kw;
        const float* wk = wck + k * 288 + c0;   // 32 contiguous uniform floats
        const u16* p0 = &vs[(((d + kd) * 100 + (h + kh) * 10) + (w + kw)) * 40];
#pragma unroll
        for (int cq = 0; cq < 4; cq++) {
          uint4 v0 = *(const uint4*)(p0 + cq * 8);
          const unsigned* u0 = (const unsigned*)&v0;
#pragma unroll
          for (int j = 0; j < 4; j++) {
            const int ce = cq * 8 + j * 2;
            acc[ce]     += bflo(u0[j]) * wk[ce];
            acc[ce + 1] += bfhi(u0[j]) * wk[ce + 1];
          }
        }
      }
    }
  }

  const int tt = b * LTOK + ((td + d) * 32 + (th + h)) * 32 + (tw + w);

  if (BF16OUT) {
    // in-place bf16 RMW on ybf
    uint4* yp = (uint4*)(ybf + (size_t)tt * CDIM + c0);
#pragma unroll
    for (int q = 0; q < 4; q++) {
      uint4 cur = yp[q];
      unsigned* cu = (unsigned*)&cur;
      unsigned pk2[4];
#pragma unroll
      for (int j = 0; j < 4; j++) {
        const int ce = q * 8 + j * 2;
        float a0 = bflo(cu[j]) + acc[ce];
        float a1 = bfhi(cu[j]) + acc[ce + 1];
        pk2[j] = (unsigned)f2bf(a0) | ((unsigned)f2bf(a1) << 16);
      }
      yp[q] = *(uint4*)pk2;
    }
  } else {
    float4* yp = (float4*)&y[(size_t)tt * CDIM + c0];
#pragma unroll
    for (int q = 0; q < 8; q++) {
      float4 cur = yp[q];
      cur.x += acc[q * 4];     cur.y += acc[q * 4 + 1];
      cur.z += acc[q * 4 + 2]; cur.w += acc[q * 4 + 3];
      yp[q] = cur;
    }
  }
}

extern "C" void kernel_launch(void* const* d_in, const int* in_sizes, int n_in,
                              void* d_out, int out_size, void* d_ws, size_t ws_size,
                              hipStream_t stream) {
  const float* x      = (const float*)d_in[0];
  // d_in[1..3] = D,H,W scalars (fixed 32)
  const float* w_qkv  = (const float*)d_in[4];
  const float* w_proj = (const float*)d_in[5];
  const float* b_proj = (const float*)d_in[6];
  const float* conv_w = (const float*)d_in[7];
  const float* conv_b = (const float*)d_in[8];
  const float* pos_w  = (const float*)d_in[9];
  const float* pos_b  = (const float*)d_in[10];
  const float* ln1_g  = (const float*)d_in[11];
  const float* ln1_b  = (const float*)d_in[12];
  const float* lin1_w = (const float*)d_in[13];
  const float* lin1_b = (const float*)d_in[14];
  const float* ln2_g  = (const float*)d_in[15];
  const float* ln2_b  = (const float*)d_in[16];
  const float* lin2_w = (const float*)d_in[17];
  const float* lin2_b = (const float*)d_in[18];
  const float* ln3_g  = (const float*)d_in[19];
  const float* ln3_b  = (const float*)d_in[20];
  const float* lin3_w = (const float*)d_in[21];
  const float* lin3_b = (const float*)d_in[22];
  const float* rpe    = (const float*)d_in[23];
  const int*   rel    = (const int*)d_in[24];
  float* out = (float*)d_out;

  // ws layout:
  //   [0, Q)         qkv (bf16), Q = 65536*864*2  -- dead after conv
  //   [Q, +497664)   wqt: w_qkv^T bf16 (864 x 288)
  //   [.., +165888)  wpt: w_proj^T bf16 (288 x 288)
  //   [.., +3024)    ptab f32
  //   [.., +31104)   wck f32 (conv weights k-major)
  //   big path: ybf bf16 (37.7 MB): attn writes bf16, conv RMWs in place, proj reads it
  //   fallback: attn f32 -> d_out; conv RMW f32; proj in-place d_out->d_out
  const size_t Q = (size_t)MROWS * NQKV * sizeof(u16);
  u16* qkv   = (u16*)d_ws;
  u16* wqt   = (u16*)((char*)d_ws + Q);
  u16* wpt   = (u16*)((char*)d_ws + Q + 497664);
  float* ptab  = (float*)((char*)d_ws + Q + 497664 + 165888);
  float* wck   = (float*)((char*)d_ws + Q + 497664 + 165888 + 3024);

  const size_t yoff = (Q + 497664 + 165888 + 3024 + 31104 + 255) & ~(size_t)255;
  const size_t ybf_bytes = (size_t)MROWS * CDIM * sizeof(u16);
  const bool big = ws_size >= yoff + ybf_bytes;
  u16* ybf = (u16*)((char*)d_ws + yoff);

  // 0. weight transforms (tiny)
  transpose_cvt<<<(NQKV * CDIM + 255) / 256, 256, 0, stream>>>(w_qkv, wqt, CDIM, NQKV);
  transpose_cvt<<<(CDIM * CDIM + 255) / 256, 256, 0, stream>>>(w_proj, wpt, CDIM, CDIM);
  conv_w_kmajor<<<(27 * 288 + 255) / 256, 256, 0, stream>>>(conv_w, wck);
  // 1. qkv = bf16(x @ w_qkv)
  gemm_areg<true, false><<<MROWS / 128, 512, 0, stream>>>(x, wqt, nullptr, qkv, NQKV);
  // 2. rpe bias tables (tiny)
  rpe_mlp<<<1, 256, 0, stream>>>(rpe, pos_w, pos_b, ln1_g, ln1_b, lin1_w, lin1_b,
                                 ln2_g, ln2_b, lin2_w, lin2_b, ln3_g, ln3_b,
                                 lin3_w, lin3_b, ptab);
  // 3..5
  if (big) {
    attn_kernel<true><<<dim3(1024, 3), 256, 0, stream>>>(qkv, ptab, rel, nullptr, ybf);
    conv_tile_kernel<true><<<dim3(128, 9), 512, 0, stream>>>(qkv, wck, conv_b, nullptr, ybf);
    gemm_areg<false, true><<<MROWS / 128, 512, 0, stream>>>(ybf, wpt, b_proj, out, CDIM);
  } else {
    attn_kernel<false><<<dim3(1024, 3), 256, 0, stream>>>(qkv, ptab, rel, out, nullptr);
    conv_tile_kernel<false><<<dim3(128, 9), 512, 0, stream>>>(qkv, wck, conv_b, out, nullptr);
    gemm_areg<false, false><<<MROWS / 128, 512, 0, stream>>>(out, wpt, b_proj, out, CDIM);
  }
}

// Round 9
// 342.589 us; speedup vs baseline: 1.8093x; 1.0572x over previous
//
#include <hip/hip_runtime.h>
#include <hip/hip_bf16.h>
#include <math.h>

#define BATCH 2
#define RES   32
#define LTOK  32768          // RES^3
#define CDIM  288
#define NQKV  864
#define MROWS 65536          // BATCH*LTOK

typedef unsigned short u16;
typedef u16   u16x4 __attribute__((ext_vector_type(4)));
typedef short s16x8 __attribute__((ext_vector_type(8)));   // 8 bf16 in 4 VGPRs (MFMA A/B frag)
typedef float f32x4 __attribute__((ext_vector_type(4)));   // MFMA C/D frag

__device__ __forceinline__ u16 f2bf(float f) {
  union { __hip_bfloat16 h; u16 u; } x;
  x.h = __float2bfloat16(f);
  return x.u;
}
__device__ __forceinline__ float bf2f(u16 u) {
  union { u16 u; __hip_bfloat16 h; } x;
  x.u = u;
  return __bfloat162float(x.h);
}
// bf16 pair unpack from packed u32 (lo = even channel, hi = odd channel)
__device__ __forceinline__ float bflo(unsigned u) {
  union { unsigned u; float f; } x; x.u = u << 16; return x.f;
}
__device__ __forceinline__ float bfhi(unsigned u) {
  union { unsigned u; float f; } x; x.u = u & 0xffff0000u; return x.f;
}

// async 16B global->LDS copy (per-lane global src, wave-uniform LDS base + lane*16)
#define ASYNC16(gsrc, ldst)                                                        \
  __builtin_amdgcn_global_load_lds(                                                \
      (const __attribute__((address_space(1))) void*)(gsrc),                       \
      (__attribute__((address_space(3))) void*)(ldst), 16, 0, 0)

// ---------------- weight transpose+convert: W (K x N) f32 -> Wt (N x K) bf16 ----------------
__global__ __launch_bounds__(256) void transpose_cvt(
    const float* __restrict__ w, u16* __restrict__ wt, int K, int N) {
  int o = blockIdx.x * 256 + threadIdx.x;
  if (o >= N * K) return;
  int n = o / K, k = o - n * K;
  wt[o] = f2bf(w[(size_t)k * N + n]);
}

// conv weights (C,1,3,3,3) -> k-major [27][288]
__global__ __launch_bounds__(256) void conv_w_kmajor(
    const float* __restrict__ cw, float* __restrict__ wck) {
  int o = blockIdx.x * 256 + threadIdx.x;
  if (o >= 27 * 288) return;
  int k = o / 288, c = o - k * 288;
  wck[o] = cw[c * 27 + k];
}

// ---------------- A-in-register GEMM: out = A(M x 288) @ Bt(N x 288)^T (+bias) ----------------
// (unchanged -- verified config)
template <bool BF16OUT, bool ABF16>
__global__ __launch_bounds__(512, 2) void gemm_areg(
    const void* __restrict__ Ax, const u16* __restrict__ Bt,
    const float* __restrict__ bias, void* __restrict__ out, int N) {
  __shared__ __align__(16) u16 lds[36864];  // 73728 B: A-stage, then B dbuf [2][9216 u16]
  const int bm = blockIdx.x * 128;
  const int tid = threadIdx.x;
  const int lane = tid & 63, wave = tid >> 6;
  const int m16 = lane & 15, kq = lane >> 4;
  const int nf = wave >> 2, mg = wave & 3;
  const int NC = N >> 5;                    // 32-col chunks

  if (ABF16) {
    const u16* Ab = (const u16*)Ax;
    for (int i = wave; i < 72; i += 8) {
      int g = i >> 1, rh = i & 1;
      ASYNC16(Ab + (size_t)(bm + rh * 64 + lane) * 288 + g * 8, &lds[i * 512]);
    }
    asm volatile("s_waitcnt vmcnt(0)" ::: "memory");
  } else {
    const float* Af = (const float*)Ax;
#pragma unroll
    for (int p = 0; p < 18; p++) {          // 9216 float4 / 512 thr
      int s = p * 512 + tid;
      int r = s / 72, q = s - r * 72;       // 72 float4 per row
      float4 v = *(const float4*)(Af + (size_t)(bm + r) * 288 + q * 4);
      u16x4 pk;
      pk[0] = f2bf(v.x); pk[1] = f2bf(v.y); pk[2] = f2bf(v.z); pk[3] = f2bf(v.w);
      *(u16x4*)&lds[(q >> 1) * 1024 + (r >> 6) * 512 + (r & 63) * 8 + (q & 1) * 4] = pk;
    }
  }
  __syncthreads();

  s16x8 areg[2][9];
#pragma unroll
  for (int j = 0; j < 2; j++) {
    const int row = (mg * 2 + j) * 16 + m16;
    const int base = (row >> 6) * 512 + (row & 63) * 8;
#pragma unroll
    for (int ks = 0; ks < 9; ks++)
      areg[j][ks] = *(const s16x8*)&lds[(ks * 4 + kq) * 1024 + base];
  }
  asm volatile("s_waitcnt lgkmcnt(0)" ::: "memory");
  __builtin_amdgcn_s_barrier();             // all waves done reading A before B overwrites

  {
    const int r = lane & 31, gh = lane >> 5;
    for (int gp = wave; gp < 18; gp += 8)
      ASYNC16(Bt + (size_t)r * 288 + (gp * 2 + gh) * 8, &lds[gp * 512]);
  }
  asm volatile("s_waitcnt vmcnt(0)" ::: "memory");
  __builtin_amdgcn_s_barrier();

  int buf = 0;
  for (int c = 0; c < NC; c++) {
    if (c + 1 < NC) {
      const u16* Bc = Bt + (size_t)(c + 1) * 32 * 288;
      const int r = lane & 31, gh = lane >> 5;
      u16* bb1 = &lds[(buf ^ 1) * 9216];
      for (int gp = wave; gp < 18; gp += 8)
        ASYNC16(Bc + (size_t)r * 288 + (gp * 2 + gh) * 8, &bb1[gp * 512]);
    }
    __builtin_amdgcn_sched_barrier(0);      // loads strictly precede stores (vmcnt count)

    const u16* bb = &lds[buf * 9216];
    f32x4 acc0 = {0.f, 0.f, 0.f, 0.f}, acc1 = {0.f, 0.f, 0.f, 0.f};
#pragma unroll
    for (int ks = 0; ks < 9; ks++) {
      s16x8 bf = *(const s16x8*)&bb[(ks * 4 + kq) * 256 + (nf * 16 + m16) * 8];
      acc0 = __builtin_amdgcn_mfma_f32_16x16x32_bf16(areg[0][ks], bf, acc0, 0, 0, 0);
      acc1 = __builtin_amdgcn_mfma_f32_16x16x32_bf16(areg[1][ks], bf, acc1, 0, 0, 0);
    }
    const int col = (c << 5) + nf * 16 + m16;
    const size_t r0 = (size_t)(bm + mg * 32 + kq * 4);
    if (BF16OUT) {
      u16* op = (u16*)out;
#pragma unroll
      for (int r = 0; r < 4; r++) {
        op[(r0 + r) * N + col] = f2bf(acc0[r]);
        op[(r0 + 16 + r) * N + col] = f2bf(acc1[r]);
      }
    } else {
      const float bv = bias ? bias[col] : 0.f;
      float* op = (float*)out;
#pragma unroll
      for (int r = 0; r < 4; r++) {
        op[(r0 + r) * N + col] = acc0[r] + bv;
        op[(r0 + 16 + r) * N + col] = acc1[r] + bv;
      }
    }
    if (c + 1 < NC) {
      asm volatile("s_waitcnt vmcnt(8)" ::: "memory");   // 8 newest = my stores; stage loads done
      __builtin_amdgcn_s_barrier();
    }
    buf ^= 1;
  }
}

// ---------------- tiny RPE-bias MLP: (3,63,3) -> (3,63,4) ----------------
__device__ __forceinline__ void ln_relu6(const float* x, float* o,
                                         const float* g, const float* b) {
  float m = 0.f;
#pragma unroll
  for (int i = 0; i < 6; i++) m += x[i];
  m *= (1.f / 6.f);
  float v = 0.f;
#pragma unroll
  for (int i = 0; i < 6; i++) { float d = x[i] - m; v += d * d; }
  v *= (1.f / 6.f);
  float r = rsqrtf(v + 1e-5f);
#pragma unroll
  for (int i = 0; i < 6; i++) {
    float t = (x[i] - m) * r * g[i] + b[i];
    o[i] = t > 0.f ? t : 0.f;
  }
}

__global__ __launch_bounds__(256) void rpe_mlp(
    const float* __restrict__ rpe, const float* __restrict__ pw, const float* __restrict__ pb,
    const float* __restrict__ g1, const float* __restrict__ b1,
    const float* __restrict__ w1, const float* __restrict__ bb1,
    const float* __restrict__ g2, const float* __restrict__ b2,
    const float* __restrict__ w2, const float* __restrict__ bb2,
    const float* __restrict__ g3, const float* __restrict__ b3,
    const float* __restrict__ w3, const float* __restrict__ bb3,
    float* __restrict__ ptab) {
  int t = blockIdx.x * blockDim.x + threadIdx.x;
  if (t >= 3 * 63) return;
  int bi = t / 63, row = t % 63;
  float p[6], q[6];
#pragma unroll
  for (int j = 0; j < 6; j++) {
    float s = pb[bi * 6 + j];
#pragma unroll
    for (int i = 0; i < 3; i++) s += rpe[(bi * 63 + row) * 3 + i] * pw[(bi * 3 + i) * 6 + j];
    p[j] = s;
  }
  ln_relu6(p, q, g1 + bi * 6, b1 + bi * 6);
#pragma unroll
  for (int j = 0; j < 6; j++) {
    float s = bb1[bi * 6 + j];
#pragma unroll
    for (int i = 0; i < 6; i++) s += q[i] * w1[(bi * 6 + i) * 6 + j];
    p[j] = s;
  }
  ln_relu6(p, q, g2 + bi * 6, b2 + bi * 6);
#pragma unroll
  for (int j = 0; j < 6; j++) {
    float s = bb2[bi * 6 + j];
#pragma unroll
    for (int i = 0; i < 6; i++) s += q[i] * w2[(bi * 6 + i) * 6 + j];
    p[j] = s;
  }
  ln_relu6(p, q, g3 + bi * 6, b3 + bi * 6);
#pragma unroll
  for (int h = 0; h < 4; h++) {
    float s = bb3[bi * 4 + h];
#pragma unroll
    for (int i = 0; i < 6; i++) s += q[i] * w3[(bi * 6 + i) * 4 + h];
    ptab[(bi * 63 + row) * 4 + h] = s;
  }
}

// ---------------- windowed attention via MFMA: 4 windows per 256-thr block ----------------
// (unchanged from R8 -- verified)
template <bool BF16OUT>
__global__ __launch_bounds__(256) void attn_kernel(
    const u16* __restrict__ qkv, const float* __restrict__ ptab,
    const int* __restrict__ rel, float* __restrict__ y, u16* __restrict__ ybf) {
  __shared__ __align__(16) u16 sq[4][640];     // [n][40]: k 0..23 data, 24..31 zero
  __shared__ __align__(16) u16 sk[4][640];
  __shared__ __align__(16) u16 sv[4][640];     // [m][40]: e 0..23 data, e24 = 1.0, 25..31 zero
  __shared__ __align__(16) u16 sps[4][640];    // [n][40]: m 0..15 hi, 16..31 lo

  const int bi = blockIdx.y;
  const int wsh = (bi == 2) ? 1 : 2;            // log2(Wsp)
  const int hsh = (bi == 2) ? 2 : 1;            // log2(Hsp)
  const int Wm1 = (1 << wsh) - 1, Hm1 = (1 << hsh) - 1;
  const int nW = RES >> wsh, nH = RES >> hsh;
  const int tid = threadIdx.x;
  const int wv = tid >> 6, lane = tid & 63;
  const int wid = blockIdx.x * 4 + wv;          // 0..4095
  const int b = wid >> 11;
  const int r_ = wid & 2047;
  const int w0 = r_ % nW;
  const int r2 = r_ / nW;
  const int h0 = r2 % nH;
  const int d0 = r2 / nH;

  u16* q_  = sq[wv];
  u16* k_  = sk[wv];
  u16* v_  = sv[wv];
  u16* ps_ = sps[wv];
  const int m16 = lane & 15, q4 = lane >> 4;

  // ---- pads: q/k cols 24..31 zero; v cols 24..31 = {1.0, 0...} (sum column at e=24) ----
  if (lane < 16) {
    uint4 z = make_uint4(0u, 0u, 0u, 0u);
    *(uint4*)&q_[lane * 40 + 24] = z;
    *(uint4*)&k_[lane * 40 + 24] = z;
    *(uint4*)&v_[lane * 40 + 24] = make_uint4(0x3f80u, 0u, 0u, 0u);  // bf16(1.0) at e=24
  }

  // rel gather + ptab prefetch (head-invariant rows, 4 consecutive floats per row)
  float4 pt[4];
#pragma unroll
  for (int r = 0; r < 4; r++) {
    int rv = rel[(bi * 16 + q4 * 4 + r) * 16 + m16];
    pt[r] = *(const float4*)&ptab[(size_t)(bi * 63 + rv) * 4];
  }

  // per-row output bases for n = q4*4+r (element index, valid for f32 y and u16 ybf)
  size_t ybase[4];
#pragma unroll
  for (int r = 0; r < 4; r++) {
    int n = q4 * 4 + r;
    int dd = n >> 3, hh2 = (n >> wsh) & Hm1, ww = n & Wm1;
    int l = ((d0 * 2 + dd) * RES + ((h0 << hsh) + hh2)) * RES + ((w0 << wsh) + ww);
    ybase[r] = (size_t)(b * LTOK + l) * CDIM + bi * 96;
  }

  // staging geometry (lane < 48): token sn, 8-ch chunk sc
  const int sn = lane / 3, sc = (lane % 3) * 8;
  size_t sbase = 0;
  if (lane < 48) {
    int dd = sn >> 3, hh2 = (sn >> wsh) & Hm1, ww = sn & Wm1;
    int l = ((d0 * 2 + dd) * RES + ((h0 << hsh) + hh2)) * RES + ((w0 << wsh) + ww);
    sbase = (size_t)(b * LTOK + l) * NQKV + bi * 96 + sc;
  }

  const float scale = 0.20412414523193154f;  // 1/sqrt(24)

  // prefetch head 0
  uint4 pq, pk, pv;
  if (lane < 48) {
    pq = *(const uint4*)(qkv + sbase);
    pk = *(const uint4*)(qkv + sbase + 288);
    pv = *(const uint4*)(qkv + sbase + 576);
  }

#pragma unroll
  for (int hd = 0; hd < 4; hd++) {
    // stage current head to LDS (vector stores; v natural [m][e])
    if (lane < 48) {
      *(uint4*)&q_[sn * 40 + sc] = pq;
      *(uint4*)&k_[sn * 40 + sc] = pk;
      *(uint4*)&v_[sn * 40 + sc] = pv;
    }
    // prefetch next head (latency hides under this head's compute)
    if (hd < 3 && lane < 48) {
      size_t nb = sbase + (size_t)(hd + 1) * 24;
      pq = *(const uint4*)(qkv + nb);
      pk = *(const uint4*)(qkv + nb + 288);
      pv = *(const uint4*)(qkv + nb + 576);
    }

    // ---- scores: one MFMA (D: col=m16 -> key m, rows q4*4+r -> query n) ----
    s16x8 af = *(const s16x8*)&q_[m16 * 40 + q4 * 8];
    s16x8 bf = *(const s16x8*)&k_[m16 * 40 + q4 * 8];
    f32x4 sc_ = __builtin_amdgcn_mfma_f32_16x16x32_bf16(af, bf, (f32x4){0.f, 0.f, 0.f, 0.f}, 0, 0, 0);

#pragma unroll
    for (int r = 0; r < 4; r++) {
      const float* ptr4 = (const float*)&pt[r];
      float s = sc_[r] * scale + ptr4[hd];
      float e = expf(s);                       // |s| <= ~0.7: no max subtraction needed
      u16 hi = f2bf(e);
      float lo = e - bf2f(hi);
      ps_[(q4 * 4 + r) * 40 + m16] = hi;
      ps_[(q4 * 4 + r) * 40 + 16 + m16] = f2bf(lo);
    }

    // ---- PV: 2 MFMAs; B-frags assembled from natural V via scalar reads ----
    s16x8 pa = *(const s16x8*)&ps_[m16 * 40 + q4 * 8];
    s16x8 v1, v2;
    const int mrow = (q4 & 1) * 8;
#pragma unroll
    for (int j = 0; j < 8; j++) {
      v1[j] = (short)v_[(mrow + j) * 40 + m16];          // e = m16       (0..15)
      v2[j] = (short)v_[(mrow + j) * 40 + 16 + m16];     // e = 16 + m16  (16..31; 24=ones)
    }
    f32x4 o1 = __builtin_amdgcn_mfma_f32_16x16x32_bf16(pa, v1, (f32x4){0.f, 0.f, 0.f, 0.f}, 0, 0, 0);
    f32x4 o2 = __builtin_amdgcn_mfma_f32_16x16x32_bf16(pa, v2, (f32x4){0.f, 0.f, 0.f, 0.f}, 0, 0, 0);

#pragma unroll
    for (int r = 0; r < 4; r++) {
      float sum = __shfl(o2[r], (lane & 48) + 8);        // e=24 ones-column = denominator
      float inv = 1.f / sum;
      if (BF16OUT) {
        u16* yp = ybf + ybase[r] + hd * 24;
        yp[m16] = f2bf(o1[r] * inv);
        if (m16 < 8) yp[16 + m16] = f2bf(o2[r] * inv);
      } else {
        float* yp = y + ybase[r] + hd * 24;
        yp[m16] = o1[r] * inv;
        if (m16 < 8) yp[16 + m16] = o2[r] * inv;
      }
    }
  }
}

// ---------------- depthwise 3x3x3 conv on V (bf16) ----------------
// one block = 8x8x8 token tile x 16 channels (was 32), 512 threads (1 token/thread).
// Halo 10^3 tokens, token stride 24 u16 = 48 B: 16B-aligned; bank-start
// 12*t mod 32 hits all 8 x4-offsets uniformly over t mod 8 = (2h+w) mod 8
// -> structural-minimum b128 conflicts. LDS 48 KB -> 3 blocks/CU = 24 waves/CU
// (was 80 KB -> 2 blocks = 16 waves: the latency-bound fix).
// Weights k-major [27][288]: 16 contiguous uniform floats per tap.
template <bool BF16OUT>
__global__ __launch_bounds__(512, 6) void conv_tile_kernel(
    const u16* __restrict__ qkv, const float* __restrict__ wck,
    const float* __restrict__ cb, float* __restrict__ y, u16* __restrict__ ybf) {
  __shared__ __align__(16) u16 vs[1000 * 24];   // 48000 B
  const int tid = threadIdx.x;
  const int bx = blockIdx.x;           // 0..127 : b*64 + tile
  const int c0 = blockIdx.y * 16;      // channel group 0..17
  const int b = bx >> 6;
  const int t = bx & 63;
  const int td = (t >> 4) * 8, th = ((t >> 2) & 3) * 8, tw = (t & 3) * 8;

  // ---- stage V halo tile (10x10x10 tokens x 16 ch bf16; 2 x 16B chunks/token) ----
#pragma unroll
  for (int p = 0; p < 4; p++) {
    int idx = p * 512 + tid;
    if (idx < 2000) {
      int tok = idx >> 1, chunk = idx & 1;
      int dz = tok / 100, rem = tok - dz * 100;
      int hz = rem / 10, wz = rem - hz * 10;
      int d = td + dz - 1, h = th + hz - 1, w = tw + wz - 1;
      uint4 v = make_uint4(0u, 0u, 0u, 0u);
      if ((unsigned)d < 32u && (unsigned)h < 32u && (unsigned)w < 32u)
        v = *(const uint4*)(qkv +
              ((size_t)(b * LTOK + ((d * 32 + h) * 32 + w))) * NQKV + 576 + c0 + chunk * 8);
      *(uint4*)&vs[tok * 24 + chunk * 8] = v;
    }
  }
  __syncthreads();

  // ---- compute: thread owns token (d,h,w) ----
  const int d = tid >> 6, h = (tid >> 3) & 7, w = tid & 7;
  float acc[16];
#pragma unroll
  for (int c = 0; c < 16; c++) acc[c] = cb[c0 + c];

  for (int kd = 0; kd < 3; kd++) {
#pragma unroll
    for (int kh = 0; kh < 3; kh++) {
#pragma unroll
      for (int kw = 0; kw < 3; kw++) {
        const int k = kd * 9 + kh * 3 + kw;
        const float* wk = wck + k * 288 + c0;   // 16 contiguous uniform floats
        const u16* p0 = &vs[(((d + kd) * 100 + (h + kh) * 10) + (w + kw)) * 24];
#pragma unroll
        for (int cq = 0; cq < 2; cq++) {
          uint4 v0 = *(const uint4*)(p0 + cq * 8);
          const unsigned* u0 = (const unsigned*)&v0;
#pragma unroll
          for (int j = 0; j < 4; j++) {
            const int ce = cq * 8 + j * 2;
            acc[ce]     += bflo(u0[j]) * wk[ce];
            acc[ce + 1] += bfhi(u0[j]) * wk[ce + 1];
          }
        }
      }
    }
  }

  const int tt = b * LTOK + ((td + d) * 32 + (th + h)) * 32 + (tw + w);

  if (BF16OUT) {
    // in-place bf16 RMW on ybf (2 x uint4)
    uint4* yp = (uint4*)(ybf + (size_t)tt * CDIM + c0);
#pragma unroll
    for (int q = 0; q < 2; q++) {
      uint4 cur = yp[q];
      unsigned* cu = (unsigned*)&cur;
      unsigned pk2[4];
#pragma unroll
      for (int j = 0; j < 4; j++) {
        const int ce = q * 8 + j * 2;
        float a0 = bflo(cu[j]) + acc[ce];
        float a1 = bfhi(cu[j]) + acc[ce + 1];
        pk2[j] = (unsigned)f2bf(a0) | ((unsigned)f2bf(a1) << 16);
      }
      yp[q] = *(uint4*)pk2;
    }
  } else {
    float4* yp = (float4*)&y[(size_t)tt * CDIM + c0];
#pragma unroll
    for (int q = 0; q < 4; q++) {
      float4 cur = yp[q];
      cur.x += acc[q * 4];     cur.y += acc[q * 4 + 1];
      cur.z += acc[q * 4 + 2]; cur.w += acc[q * 4 + 3];
      yp[q] = cur;
    }
  }
}

extern "C" void kernel_launch(void* const* d_in, const int* in_sizes, int n_in,
                              void* d_out, int out_size, void* d_ws, size_t ws_size,
                              hipStream_t stream) {
  const float* x      = (const float*)d_in[0];
  // d_in[1..3] = D,H,W scalars (fixed 32)
  const float* w_qkv  = (const float*)d_in[4];
  const float* w_proj = (const float*)d_in[5];
  const float* b_proj = (const float*)d_in[6];
  const float* conv_w = (const float*)d_in[7];
  const float* conv_b = (const float*)d_in[8];
  const float* pos_w  = (const float*)d_in[9];
  const float* pos_b  = (const float*)d_in[10];
  const float* ln1_g  = (const float*)d_in[11];
  const float* ln1_b  = (const float*)d_in[12];
  const float* lin1_w = (const float*)d_in[13];
  const float* lin1_b = (const float*)d_in[14];
  const float* ln2_g  = (const float*)d_in[15];
  const float* ln2_b  = (const float*)d_in[16];
  const float* lin2_w = (const float*)d_in[17];
  const float* lin2_b = (const float*)d_in[18];
  const float* ln3_g  = (const float*)d_in[19];
  const float* ln3_b  = (const float*)d_in[20];
  const float* lin3_w = (const float*)d_in[21];
  const float* lin3_b = (const float*)d_in[22];
  const float* rpe    = (const float*)d_in[23];
  const int*   rel    = (const int*)d_in[24];
  float* out = (float*)d_out;

  // ws layout:
  //   [0, Q)         qkv (bf16), Q = 65536*864*2  -- dead after conv
  //   [Q, +497664)   wqt: w_qkv^T bf16 (864 x 288)
  //   [.., +165888)  wpt: w_proj^T bf16 (288 x 288)
  //   [.., +3024)    ptab f32
  //   [.., +31104)   wck f32 (conv weights k-major)
  //   big path: ybf bf16 (37.7 MB): attn writes bf16, conv RMWs in place, proj reads it
  //   fallback: attn f32 -> d_out; conv RMW f32; proj in-place d_out->d_out
  const size_t Q = (size_t)MROWS * NQKV * sizeof(u16);
  u16* qkv   = (u16*)d_ws;
  u16* wqt   = (u16*)((char*)d_ws + Q);
  u16* wpt   = (u16*)((char*)d_ws + Q + 497664);
  float* ptab  = (float*)((char*)d_ws + Q + 497664 + 165888);
  float* wck   = (float*)((char*)d_ws + Q + 497664 + 165888 + 3024);

  const size_t yoff = (Q + 497664 + 165888 + 3024 + 31104 + 255) & ~(size_t)255;
  const size_t ybf_bytes = (size_t)MROWS * CDIM * sizeof(u16);
  const bool big = ws_size >= yoff + ybf_bytes;
  u16* ybf = (u16*)((char*)d_ws + yoff);

  // 0. weight transforms (tiny)
  transpose_cvt<<<(NQKV * CDIM + 255) / 256, 256, 0, stream>>>(w_qkv, wqt, CDIM, NQKV);
  transpose_cvt<<<(CDIM * CDIM + 255) / 256, 256, 0, stream>>>(w_proj, wpt, CDIM, CDIM);
  conv_w_kmajor<<<(27 * 288 + 255) / 256, 256, 0, stream>>>(conv_w, wck);
  // 1. qkv = bf16(x @ w_qkv)
  gemm_areg<true, false><<<MROWS / 128, 512, 0, stream>>>(x, wqt, nullptr, qkv, NQKV);
  // 2. rpe bias tables (tiny)
  rpe_mlp<<<1, 256, 0, stream>>>(rpe, pos_w, pos_b, ln1_g, ln1_b, lin1_w, lin1_b,
                                 ln2_g, ln2_b, lin2_w, lin2_b, ln3_g, ln3_b,
                                 lin3_w, lin3_b, ptab);
  // 3..5
  if (big) {
    attn_kernel<true><<<dim3(1024, 3), 256, 0, stream>>>(qkv, ptab, rel, nullptr, ybf);
    conv_tile_kernel<true><<<dim3(128, 18), 512, 0, stream>>>(qkv, wck, conv_b, nullptr, ybf);
    gemm_areg<false, true><<<MROWS / 128, 512, 0, stream>>>(ybf, wpt, b_proj, out, CDIM);
  } else {
    attn_kernel<false><<<dim3(1024, 3), 256, 0, stream>>>(qkv, ptab, rel, out, nullptr);
    conv_tile_kernel<false><<<dim3(128, 18), 512, 0, stream>>>(qkv, wck, conv_b, out, nullptr);
    gemm_areg<false, false><<<MROWS / 128, 512, 0, stream>>>(out, wpt, b_proj, out, CDIM);
  }
}